// Round 1
// baseline (4330.696 us; speedup 1.0000x reference)
//
#include <hip/hip_runtime.h>
#include <math.h>

#define B_ 8
#define S_ 1024
#define E_ 1024
#define H_ 16
#define FF_ 4096

// ---------------- RMSNorm: one block per row, E=1024, 256 threads x float4 ----------------
__global__ __launch_bounds__(256) void rmsnorm_kernel(const float* __restrict__ x,
                                                      const float* __restrict__ g,
                                                      float* __restrict__ out) {
  const int row = blockIdx.x;
  const int t = threadIdx.x;
  const float4 v = ((const float4*)(x + (size_t)row * E_))[t];
  float ss = v.x * v.x + v.y * v.y + v.z * v.z + v.w * v.w;
#pragma unroll
  for (int off = 32; off > 0; off >>= 1) ss += __shfl_down(ss, off);
  __shared__ float sred[4];
  if ((t & 63) == 0) sred[t >> 6] = ss;
  __syncthreads();
  const float tot = sred[0] + sred[1] + sred[2] + sred[3];
  const float rinv = rsqrtf(tot * (1.0f / E_) + 1.1920929e-07f);
  const float4 gv = ((const float4*)g)[t];
  float4 o;
  o.x = v.x * rinv * gv.x;
  o.y = v.y * rinv * gv.y;
  o.z = v.z * rinv * gv.z;
  o.w = v.w * rinv * gv.w;
  ((float4*)(out + (size_t)row * E_))[t] = o;
}

// ---------------- fp32 GEMM: C[M,N] = A[M,K] @ W[K,N] + bias (+res) (ReLU opt) ----------
// 128x128 block tile, BK=8, 256 threads, 8x8 micro-tile split as 4+4 strided halves
// (LDS read lanes land 2-way per bank -> conflict-free per m136).
template <int RELU, int RES>
__global__ __launch_bounds__(256) void gemm128(const float* __restrict__ A,
                                               const float* __restrict__ W,
                                               const float* __restrict__ bias,
                                               const float* __restrict__ res,
                                               float* __restrict__ C,
                                               int M, int N, int K) {
  __shared__ float As[8][128];  // [k][m]
  __shared__ float Ws[8][128];  // [k][n]
  const int tid = threadIdx.x;
  const int bm = blockIdx.y * 128;
  const int bn = blockIdx.x * 128;
  const int tr = (tid >> 4) & 15;
  const int tc = tid & 15;

  float acc[8][8];
#pragma unroll
  for (int i = 0; i < 8; ++i)
#pragma unroll
    for (int j = 0; j < 8; ++j) acc[i][j] = 0.0f;

  const int arow = tid >> 1;         // 0..127
  const int akq = (tid & 1) * 4;     // 0 or 4
  const int wrow = tid >> 5;         // 0..7
  const int wnq = (tid & 31) * 4;    // 0..124
  const float* Aptr = A + (size_t)(bm + arow) * K + akq;
  const float* Wptr = W + (size_t)wrow * N + (bn + wnq);

  for (int k0 = 0; k0 < K; k0 += 8) {
    const float4 av = *(const float4*)Aptr;
    const float4 wv = *(const float4*)Wptr;
    Aptr += 8;
    Wptr += (size_t)8 * N;
    __syncthreads();
    As[akq + 0][arow] = av.x;
    As[akq + 1][arow] = av.y;
    As[akq + 2][arow] = av.z;
    As[akq + 3][arow] = av.w;
    *(float4*)&Ws[wrow][wnq] = wv;
    __syncthreads();
#pragma unroll
    for (int kk = 0; kk < 8; ++kk) {
      float a[8], w[8];
      *(float4*)&a[0] = *(const float4*)&As[kk][tr * 4];
      *(float4*)&a[4] = *(const float4*)&As[kk][64 + tr * 4];
      *(float4*)&w[0] = *(const float4*)&Ws[kk][tc * 4];
      *(float4*)&w[4] = *(const float4*)&Ws[kk][64 + tc * 4];
#pragma unroll
      for (int i = 0; i < 8; ++i)
#pragma unroll
        for (int j = 0; j < 8; ++j) acc[i][j] += a[i] * w[j];
    }
  }

  // epilogue: rows {bm+tr*4+i, bm+64+tr*4+i}, cols {bn+tc*4+j, bn+64+tc*4+j}
#pragma unroll
  for (int i = 0; i < 8; ++i) {
    const int mrow = bm + ((i < 4) ? (tr * 4 + i) : (64 + tr * 4 + (i - 4)));
    const size_t rowoff = (size_t)mrow * N;
#pragma unroll
    for (int half = 0; half < 2; ++half) {
      const int col = bn + half * 64 + tc * 4;
      const float4 bv = *(const float4*)&bias[col];
      float4 o;
      o.x = acc[i][half * 4 + 0] + bv.x;
      o.y = acc[i][half * 4 + 1] + bv.y;
      o.z = acc[i][half * 4 + 2] + bv.z;
      o.w = acc[i][half * 4 + 3] + bv.w;
      if (RES) {
        const float4 rv = *(const float4*)&res[rowoff + col];
        o.x += rv.x; o.y += rv.y; o.z += rv.z; o.w += rv.w;
      }
      if (RELU) {
        o.x = fmaxf(o.x, 0.0f); o.y = fmaxf(o.y, 0.0f);
        o.z = fmaxf(o.z, 0.0f); o.w = fmaxf(o.w, 0.0f);
      }
      *(float4*)&C[rowoff + col] = o;
    }
  }
}

// ---------------- RoPE (rotate-half, theta=10000) on Q and K in-place ------------------
// one thread per (b,s,h,freq<32)
__global__ __launch_bounds__(256) void rope_kernel(float* __restrict__ Q, float* __restrict__ K) {
  const int i = blockIdx.x * 256 + threadIdx.x;  // 0 .. B*S*H*32-1
  const int fi = i & 31;
  const int h = (i >> 5) & 15;
  const int bs = i >> 9;  // b*S + s
  const int s = bs & (S_ - 1);
  const float inv = powf(10000.0f, -(float)fi * (1.0f / 32.0f));
  const float ang = (float)s * inv;
  const float cs = cosf(ang), sn = sinf(ang);
  const size_t base = (size_t)bs * E_ + h * 64 + fi;
  const float q1 = Q[base], q2 = Q[base + 32];
  Q[base] = q1 * cs - q2 * sn;
  Q[base + 32] = q2 * cs + q1 * sn;
  const float k1 = K[base], k2 = K[base + 32];
  K[base] = k1 * cs - k2 * sn;
  K[base + 32] = k2 * cs + k1 * sn;
}

// ---------------- Flash attention: block = (q-tile of 64 rows, b*h) --------------------
// 256 threads: thread = (q-row r = tid>>2, col-group c = tid&3).
// KsT[k-dim][key] transposed for broadcast float4 reads; Vs[key][d].
// Online softmax; P exchanged across the row's 4 lanes via __shfl.
__global__ __launch_bounds__(256) void attn_kernel(const float* __restrict__ Q,
                                                   const float* __restrict__ Kg,
                                                   const float* __restrict__ Vg,
                                                   float* __restrict__ O) {
  __shared__ float KsT[64][68];
  __shared__ float Vs[64][68];
  const int tid = threadIdx.x;
  const int qt = blockIdx.x;   // 0..15
  const int bh = blockIdx.y;   // 0..127
  const int b = bh >> 4, h = bh & 15;
  const int r = tid >> 2;
  const int c = tid & 3;
  const int qs = qt * 64 + r;

  const float* qrow = Q + ((size_t)(b * S_ + qs) * E_ + h * 64);
  float qreg[64];
#pragma unroll
  for (int i = 0; i < 16; ++i) {
    const float4 v = ((const float4*)qrow)[i];
    qreg[4 * i + 0] = v.x * 0.125f;
    qreg[4 * i + 1] = v.y * 0.125f;
    qreg[4 * i + 2] = v.z * 0.125f;
    qreg[4 * i + 3] = v.w * 0.125f;
  }

  float m = -1e30f, l = 0.0f;
  float o[16];
#pragma unroll
  for (int d = 0; d < 16; ++d) o[d] = 0.0f;

  for (int kt = 0; kt < 16; ++kt) {
    __syncthreads();  // previous iteration's LDS reads done
#pragma unroll
    for (int i = 0; i < 4; ++i) {
      const int f = tid + i * 256;
      const int krow = f >> 4;
      const int cw = f & 15;
      const size_t goff = (size_t)(b * S_ + kt * 64 + krow) * E_ + h * 64 + cw * 4;
      const float4 kv = *(const float4*)(Kg + goff);
      KsT[cw * 4 + 0][krow] = kv.x;
      KsT[cw * 4 + 1][krow] = kv.y;
      KsT[cw * 4 + 2][krow] = kv.z;
      KsT[cw * 4 + 3][krow] = kv.w;
      *(float4*)&Vs[krow][cw * 4] = *(const float4*)(Vg + goff);
    }
    __syncthreads();

    // scores for 16 columns j = c*16 + jj
    float p[16];
#pragma unroll
    for (int jj = 0; jj < 16; ++jj) p[jj] = 0.0f;
#pragma unroll
    for (int kk = 0; kk < 64; ++kk) {
      const float qk = qreg[kk];
      const float4* kr = (const float4*)&KsT[kk][c * 16];
      float kv[16];
      *(float4*)&kv[0] = kr[0];
      *(float4*)&kv[4] = kr[1];
      *(float4*)&kv[8] = kr[2];
      *(float4*)&kv[12] = kr[3];
#pragma unroll
      for (int jj = 0; jj < 16; ++jj) p[jj] += qk * kv[jj];
    }

    // row max over this k-tile (across quad lanes)
    float mx = p[0];
#pragma unroll
    for (int jj = 1; jj < 16; ++jj) mx = fmaxf(mx, p[jj]);
    mx = fmaxf(mx, __shfl_xor(mx, 1));
    mx = fmaxf(mx, __shfl_xor(mx, 2));
    const float newm = fmaxf(m, mx);
    const float alpha = __expf(m - newm);
    float rs = 0.0f;
#pragma unroll
    for (int jj = 0; jj < 16; ++jj) {
      p[jj] = __expf(p[jj] - newm);
      rs += p[jj];
    }
    rs += __shfl_xor(rs, 1);
    rs += __shfl_xor(rs, 2);
    l = l * alpha + rs;
    m = newm;
#pragma unroll
    for (int d = 0; d < 16; ++d) o[d] *= alpha;

    // o[d0..d0+15] += P[r][j] * V[j][d], d0 = c*16; P via quad shuffle
#pragma unroll
    for (int j = 0; j < 64; ++j) {
      const float pj = __shfl(p[j & 15], j >> 4, 4);
      const float4* vr = (const float4*)&Vs[j][c * 16];
      float vv[16];
      *(float4*)&vv[0] = vr[0];
      *(float4*)&vv[4] = vr[1];
      *(float4*)&vv[8] = vr[2];
      *(float4*)&vv[12] = vr[3];
#pragma unroll
      for (int d = 0; d < 16; ++d) o[d] += pj * vv[d];
    }
  }

  const float linv = 1.0f / l;
  float* orow = O + ((size_t)(b * S_ + qs) * E_ + h * 64 + c * 16);
#pragma unroll
  for (int i = 0; i < 4; ++i) {
    float4 ov;
    ov.x = o[4 * i + 0] * linv;
    ov.y = o[4 * i + 1] * linv;
    ov.z = o[4 * i + 2] * linv;
    ov.w = o[4 * i + 3] * linv;
    ((float4*)orow)[i] = ov;
  }
}

extern "C" void kernel_launch(void* const* d_in, const int* in_sizes, int n_in,
                              void* d_out, int out_size, void* d_ws, size_t ws_size,
                              hipStream_t stream) {
  const float* x  = (const float*)d_in[0];
  const float* WQ = (const float*)d_in[1];
  const float* bQ = (const float*)d_in[2];
  const float* WK = (const float*)d_in[3];
  const float* bK = (const float*)d_in[4];
  const float* WV = (const float*)d_in[5];
  const float* bV = (const float*)d_in[6];
  const float* WO = (const float*)d_in[7];
  const float* bO = (const float*)d_in[8];
  const float* W1 = (const float*)d_in[9];
  const float* b1 = (const float*)d_in[10];
  const float* W2 = (const float*)d_in[11];
  const float* b2 = (const float*)d_in[12];
  const float* g1 = (const float*)d_in[13];
  const float* g2 = (const float*)d_in[14];
  float* out = (float*)d_out;

  const size_t MSZ = (size_t)B_ * S_ * E_;  // 8M floats
  float* ws = (float*)d_ws;
  float* h1  = ws;            // [B*S,E]  rmsnorm1 out; reused as attention O
  float* Qb  = ws + MSZ;      // Q; reused as x1 (= x + attn_out)
  float* Kb  = ws + 2 * MSZ;  // K; reused as h2 (rmsnorm2 out)
  float* Vb  = ws + 3 * MSZ;  // V
  float* mid = ws + 4 * MSZ;  // [B*S,FF] relu(h2@W1+b1), 32M floats

  const int M = B_ * S_;  // 8192

  rmsnorm_kernel<<<M, 256, 0, stream>>>(x, g1, h1);

  const dim3 gQKV(E_ / 128, M / 128);
  gemm128<0, 0><<<gQKV, 256, 0, stream>>>(h1, WQ, bQ, nullptr, Qb, M, E_, E_);
  gemm128<0, 0><<<gQKV, 256, 0, stream>>>(h1, WK, bK, nullptr, Kb, M, E_, E_);
  gemm128<0, 0><<<gQKV, 256, 0, stream>>>(h1, WV, bV, nullptr, Vb, M, E_, E_);

  rope_kernel<<<(B_ * S_ * H_ * 32) / 256, 256, 0, stream>>>(Qb, Kb);

  attn_kernel<<<dim3(16, B_ * H_), 256, 0, stream>>>(Qb, Kb, Vb, h1);  // O -> h1

  gemm128<0, 1><<<gQKV, 256, 0, stream>>>(h1, WO, bO, x, Qb, M, E_, E_);  // x1 -> Qb

  rmsnorm_kernel<<<M, 256, 0, stream>>>(Qb, g2, Kb);  // h2 -> Kb

  const dim3 gFF1(FF_ / 128, M / 128);
  gemm128<1, 0><<<gFF1, 256, 0, stream>>>(Kb, W1, b1, nullptr, mid, M, FF_, E_);

  const dim3 gFF2(E_ / 128, M / 128);
  gemm128<0, 1><<<gFF2, 256, 0, stream>>>(mid, W2, b2, Qb, out, M, E_, FF_);
}

// Round 2
// 673.452 us; speedup vs baseline: 6.4306x; 6.4306x over previous
//
#include <hip/hip_runtime.h>
#include <math.h>

#define B_ 8
#define S_ 1024
#define E_ 1024
#define H_ 16
#define FF_ 4096

typedef __attribute__((ext_vector_type(8))) short bf16x8;
typedef __attribute__((ext_vector_type(4))) float f32x4;

__device__ __forceinline__ unsigned short f2bf(float f) {
  union { float f; unsigned u; } v;
  v.f = f;
  unsigned r = v.u + 0x7fffu + ((v.u >> 16) & 1u);
  return (unsigned short)(r >> 16);
}
__device__ __forceinline__ float bf2f(unsigned short u) {
  union { unsigned u; float f; } v;
  v.u = ((unsigned)u) << 16;
  return v.f;
}

__device__ __forceinline__ void glds16(const void* g, void* l) {
  __builtin_amdgcn_global_load_lds(
      (const __attribute__((address_space(1))) unsigned int*)g,
      (__attribute__((address_space(3))) unsigned int*)l, 16, 0, 0);
}

// ---------------- weight convert+transpose: W[K][N] fp32 -> Wt[N][K] bf16 ----------------
__global__ __launch_bounds__(256) void wconvT(const float* __restrict__ W,
                                              unsigned short* __restrict__ Wt,
                                              int K, int N) {
  __shared__ float t[32][33];
  const int tx = threadIdx.x & 31, ty = threadIdx.x >> 5;
  const int n0 = blockIdx.x * 32, k0 = blockIdx.y * 32;
#pragma unroll
  for (int p = 0; p < 4; ++p)
    t[ty + p * 8][tx] = W[(size_t)(k0 + ty + p * 8) * N + n0 + tx];
  __syncthreads();
#pragma unroll
  for (int p = 0; p < 4; ++p)
    Wt[(size_t)(n0 + ty + p * 8) * K + k0 + tx] = f2bf(t[tx][ty + p * 8]);
}

// ---------------- RMSNorm: fp32 in, bf16 out; one block per row ----------------
__global__ __launch_bounds__(256) void rmsnorm_kernel(const float* __restrict__ x,
                                                      const float* __restrict__ g,
                                                      unsigned short* __restrict__ out) {
  const int row = blockIdx.x;
  const int t = threadIdx.x;
  const float4 v = ((const float4*)(x + (size_t)row * E_))[t];
  float ss = v.x * v.x + v.y * v.y + v.z * v.z + v.w * v.w;
#pragma unroll
  for (int off = 32; off > 0; off >>= 1) ss += __shfl_down(ss, off);
  __shared__ float sred[4];
  if ((t & 63) == 0) sred[t >> 6] = ss;
  __syncthreads();
  const float tot = sred[0] + sred[1] + sred[2] + sred[3];
  const float rinv = rsqrtf(tot * (1.0f / E_) + 1.1920929e-07f);
  const float4 gv = ((const float4*)g)[t];
  ushort4 o;
  o.x = f2bf(v.x * rinv * gv.x);
  o.y = f2bf(v.y * rinv * gv.y);
  o.z = f2bf(v.z * rinv * gv.z);
  o.w = f2bf(v.w * rinv * gv.w);
  ((ushort4*)(out + (size_t)row * E_))[t] = o;
}

// ---------------- bf16 MFMA GEMM (m97 pattern): C[M,N] = A[M,K] @ Bt[N,K]^T ----------------
// 128x128 tile, BK=32, 256 thr = 4 waves (2x2 of 64x64), 4x4 MFMA 16x16x32 per wave.
// Staging via global_load_lds width=16 (LDS dest = wave-uniform base + lane*16).
template <int OUT_BF16, int RELU, int RES>
__global__ __launch_bounds__(256) void gemm_bf16(const unsigned short* __restrict__ A,
                                                 const unsigned short* __restrict__ Bt,
                                                 const float* __restrict__ bias,
                                                 const float* __restrict__ res,
                                                 void* __restrict__ C,
                                                 int M, int N, int K) {
  __shared__ unsigned short As[128 * 32];
  __shared__ unsigned short Bs[128 * 32];
  const int tid = threadIdx.x;
  const int w = tid >> 6;
  const int lane = tid & 63;
  const int bm = blockIdx.y * 128, bn = blockIdx.x * 128;
  const int wm = (w & 1) * 64, wn = (w >> 1) * 64;

  f32x4 acc[4][4];
#pragma unroll
  for (int i = 0; i < 4; ++i)
#pragma unroll
    for (int j = 0; j < 4; ++j) acc[i][j] = (f32x4){0.f, 0.f, 0.f, 0.f};

  // staging: chunk c in {0,1}: rows (w*2+c)*16 + (lane>>2), k-bytes (lane&3)*16
  const unsigned short* Ap0 = A + (size_t)(bm + w * 32 + (lane >> 2)) * K + (lane & 3) * 8;
  const unsigned short* Ap1 = Ap0 + (size_t)16 * K;
  const unsigned short* Bp0 = Bt + (size_t)(bn + w * 32 + (lane >> 2)) * K + (lane & 3) * 8;
  const unsigned short* Bp1 = Bp0 + (size_t)16 * K;
  unsigned short* AsD0 = &As[w * 1024];
  unsigned short* AsD1 = AsD0 + 512;
  unsigned short* BsD0 = &Bs[w * 1024];
  unsigned short* BsD1 = BsD0 + 512;

  const int fr = lane & 15;         // fragment row (m or n)
  const int fk = (lane >> 4) * 8;   // fragment k offset

  for (int k0 = 0; k0 < K; k0 += 32) {
    __syncthreads();
    glds16(Ap0 + k0, AsD0);
    glds16(Ap1 + k0, AsD1);
    glds16(Bp0 + k0, BsD0);
    glds16(Bp1 + k0, BsD1);
    __syncthreads();
    bf16x8 a[4], b[4];
#pragma unroll
    for (int im = 0; im < 4; ++im)
      a[im] = *(const bf16x8*)&As[(wm + im * 16 + fr) * 32 + fk];
#pragma unroll
    for (int in = 0; in < 4; ++in)
      b[in] = *(const bf16x8*)&Bs[(wn + in * 16 + fr) * 32 + fk];
#pragma unroll
    for (int im = 0; im < 4; ++im)
#pragma unroll
      for (int in = 0; in < 4; ++in)
        acc[im][in] = __builtin_amdgcn_mfma_f32_16x16x32_bf16(a[im], b[in], acc[im][in], 0, 0, 0);
  }

  // epilogue: C/D layout col = lane&15, row = (lane>>4)*4 + reg
#pragma unroll
  for (int im = 0; im < 4; ++im) {
    const int row0 = bm + wm + im * 16 + (lane >> 4) * 4;
#pragma unroll
    for (int in = 0; in < 4; ++in) {
      const int col = bn + wn + in * 16 + (lane & 15);
      const float bv = bias[col];
#pragma unroll
      for (int r = 0; r < 4; ++r) {
        float v = acc[im][in][r] + bv;
        if (RES) v += res[(size_t)(row0 + r) * N + col];
        if (RELU) v = fmaxf(v, 0.0f);
        if (OUT_BF16)
          ((unsigned short*)C)[(size_t)(row0 + r) * N + col] = f2bf(v);
        else
          ((float*)C)[(size_t)(row0 + r) * N + col] = v;
      }
    }
  }
}

// ---------------- RoPE (rotate-half, theta=10000) on bf16 Q,K in-place ----------------
__global__ __launch_bounds__(256) void rope_kernel(unsigned short* __restrict__ Q,
                                                   unsigned short* __restrict__ K) {
  const int i = blockIdx.x * 256 + threadIdx.x;
  const int fi = i & 31;
  const int h = (i >> 5) & 15;
  const int bs = i >> 9;
  const int s = bs & (S_ - 1);
  const float inv = powf(10000.0f, -(float)fi * (1.0f / 32.0f));
  const float ang = (float)s * inv;
  const float cs = cosf(ang), sn = sinf(ang);
  const size_t base = (size_t)bs * E_ + h * 64 + fi;
  const float q1 = bf2f(Q[base]), q2 = bf2f(Q[base + 32]);
  Q[base] = f2bf(q1 * cs - q2 * sn);
  Q[base + 32] = f2bf(q2 * cs + q1 * sn);
  const float k1 = bf2f(K[base]), k2 = bf2f(K[base + 32]);
  K[base] = f2bf(k1 * cs - k2 * sn);
  K[base + 32] = f2bf(k2 * cs + k1 * sn);
}

// ---------------- MFMA flash attention ----------------
// block = 64 Q rows x (b,h); 4 waves, wave w owns Q rows q0..q0+15.
// Per 64-key tile: QK^T via 8 MFMAs (4 col-tiles x 2 k-chunks), online softmax on C-layout,
// P -> LDS (bf16, padded) -> A-layout frags, PV via 8 MFMAs with V^T in LDS.
__global__ __launch_bounds__(256) void attn_mfma(const unsigned short* __restrict__ Qg,
                                                 const unsigned short* __restrict__ Kg,
                                                 const unsigned short* __restrict__ Vg,
                                                 unsigned short* __restrict__ Og) {
  __shared__ unsigned short Ks[64 * 72];    // [key][d], stride 72 (pad: 2-way banks)
  __shared__ unsigned short VsT[64 * 72];   // [d][key]
  __shared__ unsigned short Ps[4][16 * 72]; // per-wave P [q][key]
  const int tid = threadIdx.x;
  const int w = tid >> 6, lane = tid & 63;
  const int qt = blockIdx.x, bh = blockIdx.y;
  const int b = bh >> 4, h = bh & 15;
  const int q0 = qt * 64 + w * 16;
  const int fr = lane & 15;
  const int fk = (lane >> 4) * 8;

  // Q fragments (persist across k-tiles): A[m=lane&15][k=(lane>>4)*8+j], k-chunks 0/32
  const size_t qoff = (size_t)(b * S_ + q0 + fr) * E_ + h * 64 + fk;
  const bf16x8 qa0 = *(const bf16x8*)(Qg + qoff);
  const bf16x8 qa1 = *(const bf16x8*)(Qg + qoff + 32);

  float m[4], l[4];
  f32x4 o[4];
#pragma unroll
  for (int r = 0; r < 4; ++r) { m[r] = -1e30f; l[r] = 0.0f; }
#pragma unroll
  for (int nt = 0; nt < 4; ++nt) o[nt] = (f32x4){0.f, 0.f, 0.f, 0.f};

  const int skey = tid >> 4;       // 0..15 (+16 per pass)
  const int sd4 = (tid & 15) * 4;  // d base for staging

  for (int kt = 0; kt < 16; ++kt) {
    __syncthreads();
#pragma unroll
    for (int p = 0; p < 4; ++p) {
      const int key = p * 16 + skey;
      const size_t g = (size_t)(b * S_ + kt * 64 + key) * E_ + h * 64 + sd4;
      const ushort4 kv = *(const ushort4*)(Kg + g);
      *(ushort4*)&Ks[key * 72 + sd4] = kv;
      const ushort4 vv = *(const ushort4*)(Vg + g);
      VsT[(sd4 + 0) * 72 + key] = vv.x;
      VsT[(sd4 + 1) * 72 + key] = vv.y;
      VsT[(sd4 + 2) * 72 + key] = vv.z;
      VsT[(sd4 + 3) * 72 + key] = vv.w;
    }
    __syncthreads();

    // QK^T: s[ct] = 16q x 16k tile, keys ct*16..ct*16+15
    f32x4 s[4];
#pragma unroll
    for (int ct = 0; ct < 4; ++ct) {
      const bf16x8 kb0 = *(const bf16x8*)&Ks[(ct * 16 + fr) * 72 + fk];
      const bf16x8 kb1 = *(const bf16x8*)&Ks[(ct * 16 + fr) * 72 + 32 + fk];
      f32x4 a = (f32x4){0.f, 0.f, 0.f, 0.f};
      a = __builtin_amdgcn_mfma_f32_16x16x32_bf16(qa0, kb0, a, 0, 0, 0);
      a = __builtin_amdgcn_mfma_f32_16x16x32_bf16(qa1, kb1, a, 0, 0, 0);
      s[ct] = a;
    }
#pragma unroll
    for (int ct = 0; ct < 4; ++ct)
#pragma unroll
      for (int r = 0; r < 4; ++r) s[ct][r] *= 0.125f;

    // online softmax; row = (lane>>4)*4 + r, cols spread across 16 lanes x 4 tiles
    float t[4];
#pragma unroll
    for (int r = 0; r < 4; ++r)
      t[r] = fmaxf(fmaxf(s[0][r], s[1][r]), fmaxf(s[2][r], s[3][r]));
#pragma unroll
    for (int mask = 1; mask < 16; mask <<= 1)
#pragma unroll
      for (int r = 0; r < 4; ++r) t[r] = fmaxf(t[r], __shfl_xor(t[r], mask));
    float alpha[4], rs[4];
#pragma unroll
    for (int r = 0; r < 4; ++r) {
      const float nm = fmaxf(m[r], t[r]);
      alpha[r] = __expf(m[r] - nm);
      m[r] = nm;
      rs[r] = 0.0f;
    }
#pragma unroll
    for (int ct = 0; ct < 4; ++ct)
#pragma unroll
      for (int r = 0; r < 4; ++r) {
        const float p = __expf(s[ct][r] - m[r]);
        s[ct][r] = p;
        rs[r] += p;
      }
#pragma unroll
    for (int mask = 1; mask < 16; mask <<= 1)
#pragma unroll
      for (int r = 0; r < 4; ++r) rs[r] += __shfl_xor(rs[r], mask);
#pragma unroll
    for (int r = 0; r < 4; ++r) l[r] = l[r] * alpha[r] + rs[r];
#pragma unroll
    for (int nt = 0; nt < 4; ++nt)
#pragma unroll
      for (int r = 0; r < 4; ++r) o[nt][r] *= alpha[r];

    // P: C-layout -> LDS (bf16) -> A-layout (same-wave, no barrier needed)
#pragma unroll
    for (int ct = 0; ct < 4; ++ct)
#pragma unroll
      for (int r = 0; r < 4; ++r)
        Ps[w][((lane >> 4) * 4 + r) * 72 + ct * 16 + fr] = f2bf(s[ct][r]);
    const bf16x8 pa0 = *(const bf16x8*)&Ps[w][fr * 72 + fk];
    const bf16x8 pa1 = *(const bf16x8*)&Ps[w][fr * 72 + 32 + fk];

    // PV: O[q][d], 4 d-tiles x 2 key-chunks; B-frag from VsT[d][key]
#pragma unroll
    for (int nt = 0; nt < 4; ++nt) {
      const bf16x8 vb0 = *(const bf16x8*)&VsT[(nt * 16 + fr) * 72 + fk];
      const bf16x8 vb1 = *(const bf16x8*)&VsT[(nt * 16 + fr) * 72 + 32 + fk];
      o[nt] = __builtin_amdgcn_mfma_f32_16x16x32_bf16(pa0, vb0, o[nt], 0, 0, 0);
      o[nt] = __builtin_amdgcn_mfma_f32_16x16x32_bf16(pa1, vb1, o[nt], 0, 0, 0);
    }
  }

  // epilogue: row = q0 + (lane>>4)*4 + r, col d = nt*16 + (lane&15)
#pragma unroll
  for (int r = 0; r < 4; ++r) {
    const int row = q0 + (lane >> 4) * 4 + r;
    const float linv = 1.0f / l[r];
    const size_t base = (size_t)(b * S_ + row) * E_ + h * 64;
#pragma unroll
    for (int nt = 0; nt < 4; ++nt)
      Og[base + nt * 16 + fr] = f2bf(o[nt][r] * linv);
  }
}

extern "C" void kernel_launch(void* const* d_in, const int* in_sizes, int n_in,
                              void* d_out, int out_size, void* d_ws, size_t ws_size,
                              hipStream_t stream) {
  const float* x  = (const float*)d_in[0];
  const float* WQ = (const float*)d_in[1];
  const float* bQ = (const float*)d_in[2];
  const float* WK = (const float*)d_in[3];
  const float* bK = (const float*)d_in[4];
  const float* WV = (const float*)d_in[5];
  const float* bV = (const float*)d_in[6];
  const float* WO = (const float*)d_in[7];
  const float* bO = (const float*)d_in[8];
  const float* W1 = (const float*)d_in[9];
  const float* b1 = (const float*)d_in[10];
  const float* W2 = (const float*)d_in[11];
  const float* b2 = (const float*)d_in[12];
  const float* g1 = (const float*)d_in[13];
  const float* g2 = (const float*)d_in[14];
  float* out = (float*)d_out;

  char* ws = (char*)d_ws;
  const size_t MB = 1024 * 1024;
  unsigned short* h1  = (unsigned short*)(ws + 0 * MB);    // [8192,1024] bf16
  unsigned short* Qb  = (unsigned short*)(ws + 16 * MB);
  unsigned short* Kb  = (unsigned short*)(ws + 32 * MB);
  unsigned short* Vb  = (unsigned short*)(ws + 48 * MB);
  unsigned short* Ob  = (unsigned short*)(ws + 64 * MB);
  float*          x1  = (float*)(ws + 80 * MB);            // [8192,1024] fp32
  unsigned short* h2  = (unsigned short*)(ws + 112 * MB);
  unsigned short* mid = (unsigned short*)(ws + 128 * MB);  // [8192,4096] bf16
  unsigned short* WQt = (unsigned short*)(ws + 192 * MB);
  unsigned short* WKt = (unsigned short*)(ws + 194 * MB);
  unsigned short* WVt = (unsigned short*)(ws + 196 * MB);
  unsigned short* WOt = (unsigned short*)(ws + 198 * MB);
  unsigned short* W1t = (unsigned short*)(ws + 200 * MB);  // [4096,1024]
  unsigned short* W2t = (unsigned short*)(ws + 208 * MB);  // [1024,4096]

  const int M = B_ * S_;  // 8192

  // weights: fp32 [K][N] -> bf16 [N][K]
  wconvT<<<dim3(32, 32), 256, 0, stream>>>(WQ, WQt, E_, E_);
  wconvT<<<dim3(32, 32), 256, 0, stream>>>(WK, WKt, E_, E_);
  wconvT<<<dim3(32, 32), 256, 0, stream>>>(WV, WVt, E_, E_);
  wconvT<<<dim3(32, 32), 256, 0, stream>>>(WO, WOt, E_, E_);
  wconvT<<<dim3(128, 32), 256, 0, stream>>>(W1, W1t, E_, FF_);
  wconvT<<<dim3(32, 128), 256, 0, stream>>>(W2, W2t, FF_, E_);

  rmsnorm_kernel<<<M, 256, 0, stream>>>(x, g1, h1);

  const dim3 gE(E_ / 128, M / 128);
  gemm_bf16<1, 0, 0><<<gE, 256, 0, stream>>>(h1, WQt, bQ, nullptr, Qb, M, E_, E_);
  gemm_bf16<1, 0, 0><<<gE, 256, 0, stream>>>(h1, WKt, bK, nullptr, Kb, M, E_, E_);
  gemm_bf16<1, 0, 0><<<gE, 256, 0, stream>>>(h1, WVt, bV, nullptr, Vb, M, E_, E_);

  rope_kernel<<<(B_ * S_ * H_ * 32) / 256, 256, 0, stream>>>(Qb, Kb);

  attn_mfma<<<dim3(16, B_ * H_), 256, 0, stream>>>(Qb, Kb, Vb, Ob);

  gemm_bf16<0, 0, 1><<<gE, 256, 0, stream>>>(Ob, WOt, bO, x, x1, M, E_, E_);

  rmsnorm_kernel<<<M, 256, 0, stream>>>(x1, g2, h2);

  const dim3 gF1(FF_ / 128, M / 128);
  gemm_bf16<1, 1, 0><<<gF1, 256, 0, stream>>>(h2, W1t, b1, nullptr, mid, M, FF_, E_);

  gemm_bf16<0, 0, 1><<<gE, 256, 0, stream>>>(mid, W2t, b2, x1, out, M, E_, FF_);
}

// Round 3
// 609.697 us; speedup vs baseline: 7.1030x; 1.1046x over previous
//
#include <hip/hip_runtime.h>
#include <math.h>

#define B_ 8
#define S_ 1024
#define E_ 1024
#define H_ 16
#define FF_ 4096

typedef __attribute__((ext_vector_type(8))) short bf16x8;
typedef __attribute__((ext_vector_type(4))) float f32x4;

__device__ __forceinline__ unsigned short f2bf(float f) {
  union { float f; unsigned u; } v;
  v.f = f;
  unsigned r = v.u + 0x7fffu + ((v.u >> 16) & 1u);
  return (unsigned short)(r >> 16);
}
__device__ __forceinline__ float bf2f(unsigned short u) {
  union { unsigned u; float f; } v;
  v.u = ((unsigned)u) << 16;
  return v.f;
}

__device__ __forceinline__ void glds16(const void* g, void* l) {
  __builtin_amdgcn_global_load_lds(
      (const __attribute__((address_space(1))) unsigned int*)g,
      (__attribute__((address_space(3))) unsigned int*)l, 16, 0, 0);
}

// ---------------- weight convert+transpose: W[K][N] fp32 -> Wt[N][K] bf16 ----------------
__global__ __launch_bounds__(256) void wconvT(const float* __restrict__ W,
                                              unsigned short* __restrict__ Wt,
                                              int K, int N) {
  __shared__ float t[32][33];
  const int tx = threadIdx.x & 31, ty = threadIdx.x >> 5;
  const int n0 = blockIdx.x * 32, k0 = blockIdx.y * 32;
#pragma unroll
  for (int p = 0; p < 4; ++p)
    t[ty + p * 8][tx] = W[(size_t)(k0 + ty + p * 8) * N + n0 + tx];
  __syncthreads();
#pragma unroll
  for (int p = 0; p < 4; ++p)
    Wt[(size_t)(n0 + ty + p * 8) * K + k0 + tx] = f2bf(t[tx][ty + p * 8]);
}

// ---------------- pack QKV biases ----------------
__global__ __launch_bounds__(256) void bpack(const float* __restrict__ bQ,
                                             const float* __restrict__ bK,
                                             const float* __restrict__ bV,
                                             float* __restrict__ o) {
  const int i = blockIdx.x * 256 + threadIdx.x;  // 0..3071
  const float v = (i < 1024) ? bQ[i] : ((i < 2048) ? bK[i - 1024] : bV[i - 2048]);
  o[i] = v;
}

// ---------------- RMSNorm: fp32 in, bf16 out; one block per row ----------------
__global__ __launch_bounds__(256) void rmsnorm_kernel(const float* __restrict__ x,
                                                      const float* __restrict__ g,
                                                      unsigned short* __restrict__ out) {
  const int row = blockIdx.x;
  const int t = threadIdx.x;
  const float4 v = ((const float4*)(x + (size_t)row * E_))[t];
  float ss = v.x * v.x + v.y * v.y + v.z * v.z + v.w * v.w;
#pragma unroll
  for (int off = 32; off > 0; off >>= 1) ss += __shfl_down(ss, off);
  __shared__ float sred[4];
  if ((t & 63) == 0) sred[t >> 6] = ss;
  __syncthreads();
  const float tot = sred[0] + sred[1] + sred[2] + sred[3];
  const float rinv = rsqrtf(tot * (1.0f / E_) + 1.1920929e-07f);
  const float4 gv = ((const float4*)g)[t];
  ushort4 o;
  o.x = f2bf(v.x * rinv * gv.x);
  o.y = f2bf(v.y * rinv * gv.y);
  o.z = f2bf(v.z * rinv * gv.z);
  o.w = f2bf(v.w * rinv * gv.w);
  ((ushort4*)(out + (size_t)row * E_))[t] = o;
}

// ---------------- bf16 MFMA GEMM (m97 pattern): C[M,N] = A[M,K] @ Bt[N,K]^T ----------------
template <int OUT_BF16, int RELU, int RES>
__global__ __launch_bounds__(256) void gemm_bf16(const unsigned short* __restrict__ A,
                                                 const unsigned short* __restrict__ Bt,
                                                 const float* __restrict__ bias,
                                                 const float* __restrict__ res,
                                                 void* __restrict__ C,
                                                 int M, int N, int K) {
  __shared__ unsigned short As[128 * 32];
  __shared__ unsigned short Bs[128 * 32];
  const int tid = threadIdx.x;
  const int w = tid >> 6;
  const int lane = tid & 63;
  const int bm = blockIdx.y * 128, bn = blockIdx.x * 128;
  const int wm = (w & 1) * 64, wn = (w >> 1) * 64;

  f32x4 acc[4][4];
#pragma unroll
  for (int i = 0; i < 4; ++i)
#pragma unroll
    for (int j = 0; j < 4; ++j) acc[i][j] = (f32x4){0.f, 0.f, 0.f, 0.f};

  const unsigned short* Ap0 = A + (size_t)(bm + w * 32 + (lane >> 2)) * K + (lane & 3) * 8;
  const unsigned short* Ap1 = Ap0 + (size_t)16 * K;
  const unsigned short* Bp0 = Bt + (size_t)(bn + w * 32 + (lane >> 2)) * K + (lane & 3) * 8;
  const unsigned short* Bp1 = Bp0 + (size_t)16 * K;
  unsigned short* AsD0 = &As[w * 1024];
  unsigned short* AsD1 = AsD0 + 512;
  unsigned short* BsD0 = &Bs[w * 1024];
  unsigned short* BsD1 = BsD0 + 512;

  const int fr = lane & 15;
  const int fk = (lane >> 4) * 8;

  for (int k0 = 0; k0 < K; k0 += 32) {
    __syncthreads();
    glds16(Ap0 + k0, AsD0);
    glds16(Ap1 + k0, AsD1);
    glds16(Bp0 + k0, BsD0);
    glds16(Bp1 + k0, BsD1);
    __syncthreads();
    bf16x8 a[4], b[4];
#pragma unroll
    for (int im = 0; im < 4; ++im)
      a[im] = *(const bf16x8*)&As[(wm + im * 16 + fr) * 32 + fk];
#pragma unroll
    for (int in = 0; in < 4; ++in)
      b[in] = *(const bf16x8*)&Bs[(wn + in * 16 + fr) * 32 + fk];
#pragma unroll
    for (int im = 0; im < 4; ++im)
#pragma unroll
      for (int in = 0; in < 4; ++in)
        acc[im][in] = __builtin_amdgcn_mfma_f32_16x16x32_bf16(a[im], b[in], acc[im][in], 0, 0, 0);
  }

#pragma unroll
  for (int im = 0; im < 4; ++im) {
    const int row0 = bm + wm + im * 16 + (lane >> 4) * 4;
#pragma unroll
    for (int in = 0; in < 4; ++in) {
      const int col = bn + wn + in * 16 + (lane & 15);
      const float bv = bias[col];
#pragma unroll
      for (int r = 0; r < 4; ++r) {
        float v = acc[im][in][r] + bv;
        if (RES) v += res[(size_t)(row0 + r) * N + col];
        if (RELU) v = fmaxf(v, 0.0f);
        if (OUT_BF16)
          ((unsigned short*)C)[(size_t)(row0 + r) * N + col] = f2bf(v);
        else
          ((float*)C)[(size_t)(row0 + r) * N + col] = v;
      }
    }
  }
}

// ---------------- RoPE on fused QKV buffer (row stride 3072): Q at +0, K at +1024 --------
__global__ __launch_bounds__(256) void rope_kernel(unsigned short* __restrict__ QKV) {
  const int i = blockIdx.x * 256 + threadIdx.x;
  const int fi = i & 31;
  const int h = (i >> 5) & 15;
  const int bs = i >> 9;
  const int s = bs & (S_ - 1);
  const float inv = powf(10000.0f, -(float)fi * (1.0f / 32.0f));
  const float ang = (float)s * inv;
  const float cs = cosf(ang), sn = sinf(ang);
  const size_t base = (size_t)bs * 3072 + h * 64 + fi;
  const float q1 = bf2f(QKV[base]), q2 = bf2f(QKV[base + 32]);
  QKV[base] = f2bf(q1 * cs - q2 * sn);
  QKV[base + 32] = f2bf(q2 * cs + q1 * sn);
  const size_t kb = base + 1024;
  const float k1 = bf2f(QKV[kb]), k2 = bf2f(QKV[kb + 32]);
  QKV[kb] = f2bf(k1 * cs - k2 * sn);
  QKV[kb + 32] = f2bf(k2 * cs + k1 * sn);
}

// ---------------- V transpose: QKV V-cols -> Vt[(b*16+h)*64 + d][s] ----------------
__global__ __launch_bounds__(256) void vtrans(const unsigned short* __restrict__ QKV,
                                              unsigned short* __restrict__ Vt) {
  __shared__ unsigned short T[64 * 66];
  const int tid = threadIdx.x;
  const int st = blockIdx.x, bh = blockIdx.y;
  const int b = bh >> 4, h = bh & 15;
  const int sx = tid & 15, sy = tid >> 4;  // sy 0..15
#pragma unroll
  for (int p = 0; p < 4; ++p) {
    const int sl = p * 16 + (sy & 15);
    const ushort4 v = *(const ushort4*)&QKV[(size_t)(b * S_ + st * 64 + sl) * 3072 + 2048 + h * 64 + sx * 4];
    *(ushort4*)&T[sl * 66 + sx * 4] = v;
  }
  __syncthreads();
#pragma unroll
  for (int p = 0; p < 4; ++p) {
    const int dl = p * 16 + (sy & 15);
    ushort4 o;
    o.x = T[(sx * 4 + 0) * 66 + dl];
    o.y = T[(sx * 4 + 1) * 66 + dl];
    o.z = T[(sx * 4 + 2) * 66 + dl];
    o.w = T[(sx * 4 + 3) * 66 + dl];
    *(ushort4*)&Vt[(size_t)(bh * 64 + dl) * S_ + st * 64 + sx * 4] = o;
  }
}

// ---------------- MFMA flash attention, fragment-major glds staging ----------------
// block = 64 Q rows x (b,h); 4 waves; K and V^T tiles staged via global_load_lds
// directly in MFMA B-fragment order (unit = tile*64 + lane, 16B each).
__global__ __launch_bounds__(256) void attn_mfma(const unsigned short* __restrict__ QKV,
                                                 const unsigned short* __restrict__ Vt,
                                                 unsigned short* __restrict__ Og) {
  __shared__ unsigned short Kf[8 * 512];   // 8 units(tiles) x 64 lanes x 8 shorts
  __shared__ unsigned short Vf[8 * 512];
  __shared__ unsigned short Ps[4][16 * 72];
  const int tid = threadIdx.x;
  const int w = tid >> 6, lane = tid & 63;
  const int qt = blockIdx.x, bh = blockIdx.y;
  const int b = bh >> 4, h = bh & 15;
  const int q0 = qt * 64 + w * 16;
  const int fr = lane & 15;
  const int fk = (lane >> 4) * 8;

  // Q fragments: A[m=lane&15][k=(lane>>4)*8+j], k-chunks 0/32 of DK=64
  const unsigned short* qp = QKV + (size_t)(b * S_ + q0 + fr) * 3072 + h * 64 + fk;
  const bf16x8 qa0 = *(const bf16x8*)qp;
  const bf16x8 qa1 = *(const bf16x8*)(qp + 32);

  float m[4], l[4];
  f32x4 o[4];
#pragma unroll
  for (int r = 0; r < 4; ++r) { m[r] = -1e30f; l[r] = 0.0f; }
#pragma unroll
  for (int nt = 0; nt < 4; ++nt) o[nt] = (f32x4){0.f, 0.f, 0.f, 0.f};

  for (int kt = 0; kt < 16; ++kt) {
    __syncthreads();
    // wave w stages K units 2w,2w+1 and V units 2w,2w+1 (unit tile = sub*2 + chunk)
#pragma unroll
    for (int p = 0; p < 2; ++p) {
      const int tk = 2 * w + p;
      const int ct = tk >> 1, chunk = tk & 1;
      // K unit: key = ct*16 + (lane&15), d = chunk*32 + (lane>>4)*8 .. +7 (contiguous)
      const unsigned short* gk = QKV + (size_t)(b * S_ + kt * 64 + ct * 16 + fr) * 3072 +
                                 1024 + h * 64 + chunk * 32 + fk;
      glds16(gk, &Kf[tk * 512]);
      // V unit: d = ct*16 + (lane&15), s = kt*64 + chunk*32 + (lane>>4)*8 .. +7
      const unsigned short* gv = Vt + (size_t)(bh * 64 + ct * 16 + fr) * S_ +
                                 kt * 64 + chunk * 32 + fk;
      glds16(gv, &Vf[tk * 512]);
    }
    __syncthreads();

    // QK^T: s[ct] = 16q x 16key tile
    f32x4 s[4];
#pragma unroll
    for (int ct = 0; ct < 4; ++ct) {
      const bf16x8 kb0 = *(const bf16x8*)&Kf[(ct * 2 + 0) * 512 + lane * 8];
      const bf16x8 kb1 = *(const bf16x8*)&Kf[(ct * 2 + 1) * 512 + lane * 8];
      f32x4 a = (f32x4){0.f, 0.f, 0.f, 0.f};
      a = __builtin_amdgcn_mfma_f32_16x16x32_bf16(qa0, kb0, a, 0, 0, 0);
      a = __builtin_amdgcn_mfma_f32_16x16x32_bf16(qa1, kb1, a, 0, 0, 0);
      s[ct] = a;
    }
#pragma unroll
    for (int ct = 0; ct < 4; ++ct)
#pragma unroll
      for (int r = 0; r < 4; ++r) s[ct][r] *= 0.125f;

    // online softmax; C-layout row = (lane>>4)*4 + r
    float t[4];
#pragma unroll
    for (int r = 0; r < 4; ++r)
      t[r] = fmaxf(fmaxf(s[0][r], s[1][r]), fmaxf(s[2][r], s[3][r]));
#pragma unroll
    for (int mask = 1; mask < 16; mask <<= 1)
#pragma unroll
      for (int r = 0; r < 4; ++r) t[r] = fmaxf(t[r], __shfl_xor(t[r], mask));
    float alpha[4], rs[4];
#pragma unroll
    for (int r = 0; r < 4; ++r) {
      const float nm = fmaxf(m[r], t[r]);
      alpha[r] = __expf(m[r] - nm);
      m[r] = nm;
      rs[r] = 0.0f;
    }
#pragma unroll
    for (int ct = 0; ct < 4; ++ct)
#pragma unroll
      for (int r = 0; r < 4; ++r) {
        const float p = __expf(s[ct][r] - m[r]);
        s[ct][r] = p;
        rs[r] += p;
      }
#pragma unroll
    for (int mask = 1; mask < 16; mask <<= 1)
#pragma unroll
      for (int r = 0; r < 4; ++r) rs[r] += __shfl_xor(rs[r], mask);
#pragma unroll
    for (int r = 0; r < 4; ++r) l[r] = l[r] * alpha[r] + rs[r];
#pragma unroll
    for (int nt = 0; nt < 4; ++nt)
#pragma unroll
      for (int r = 0; r < 4; ++r) o[nt][r] *= alpha[r];

    // P: C-layout -> LDS -> A-layout (same wave)
#pragma unroll
    for (int ct = 0; ct < 4; ++ct)
#pragma unroll
      for (int r = 0; r < 4; ++r)
        Ps[w][((lane >> 4) * 4 + r) * 72 + ct * 16 + fr] = f2bf(s[ct][r]);
    const bf16x8 pa0 = *(const bf16x8*)&Ps[w][fr * 72 + fk];
    const bf16x8 pa1 = *(const bf16x8*)&Ps[w][fr * 72 + 32 + fk];

    // PV: O[q][d]; B-frags from fragment-major Vf
#pragma unroll
    for (int nt = 0; nt < 4; ++nt) {
      const bf16x8 vb0 = *(const bf16x8*)&Vf[(nt * 2 + 0) * 512 + lane * 8];
      const bf16x8 vb1 = *(const bf16x8*)&Vf[(nt * 2 + 1) * 512 + lane * 8];
      o[nt] = __builtin_amdgcn_mfma_f32_16x16x32_bf16(pa0, vb0, o[nt], 0, 0, 0);
      o[nt] = __builtin_amdgcn_mfma_f32_16x16x32_bf16(pa1, vb1, o[nt], 0, 0, 0);
    }
  }

#pragma unroll
  for (int r = 0; r < 4; ++r) {
    const int row = q0 + (lane >> 4) * 4 + r;
    const float linv = 1.0f / l[r];
    const size_t base = (size_t)(b * S_ + row) * E_ + h * 64;
#pragma unroll
    for (int nt = 0; nt < 4; ++nt)
      Og[base + nt * 16 + fr] = f2bf(o[nt][r] * linv);
  }
}

extern "C" void kernel_launch(void* const* d_in, const int* in_sizes, int n_in,
                              void* d_out, int out_size, void* d_ws, size_t ws_size,
                              hipStream_t stream) {
  const float* x  = (const float*)d_in[0];
  const float* WQ = (const float*)d_in[1];
  const float* bQ = (const float*)d_in[2];
  const float* WK = (const float*)d_in[3];
  const float* bK = (const float*)d_in[4];
  const float* WV = (const float*)d_in[5];
  const float* bV = (const float*)d_in[6];
  const float* WO = (const float*)d_in[7];
  const float* bO = (const float*)d_in[8];
  const float* W1 = (const float*)d_in[9];
  const float* b1 = (const float*)d_in[10];
  const float* W2 = (const float*)d_in[11];
  const float* b2 = (const float*)d_in[12];
  const float* g1 = (const float*)d_in[13];
  const float* g2 = (const float*)d_in[14];
  float* out = (float*)d_out;

  char* ws = (char*)d_ws;
  const size_t MB = 1024 * 1024;
  unsigned short* h1   = (unsigned short*)(ws + 0 * MB);    // [8192,1024] bf16
  unsigned short* QKV  = (unsigned short*)(ws + 16 * MB);   // [8192,3072] bf16
  unsigned short* Vt   = (unsigned short*)(ws + 64 * MB);   // [128*64,1024] bf16
  unsigned short* Ob   = (unsigned short*)(ws + 80 * MB);   // [8192,1024] bf16
  float*          x1   = (float*)(ws + 96 * MB);            // [8192,1024] fp32
  unsigned short* h2   = (unsigned short*)(ws + 128 * MB);  // [8192,1024] bf16
  unsigned short* mid  = (unsigned short*)(ws + 16 * MB);   // [8192,4096] bf16 (reuses QKV+Vt)
  unsigned short* WQKVt= (unsigned short*)(ws + 144 * MB);  // [3072,1024] bf16
  unsigned short* WOt  = (unsigned short*)(ws + 150 * MB);  // [1024,1024]
  unsigned short* W1t  = (unsigned short*)(ws + 152 * MB);  // [4096,1024]
  unsigned short* W2t  = (unsigned short*)(ws + 160 * MB);  // [1024,4096]
  float*          bqkv = (float*)(ws + 168 * MB);           // [3072]

  const int M = B_ * S_;  // 8192

  wconvT<<<dim3(32, 32), 256, 0, stream>>>(WQ, WQKVt, E_, E_);
  wconvT<<<dim3(32, 32), 256, 0, stream>>>(WK, WQKVt + 1024 * 1024, E_, E_);
  wconvT<<<dim3(32, 32), 256, 0, stream>>>(WV, WQKVt + 2 * 1024 * 1024, E_, E_);
  wconvT<<<dim3(32, 32), 256, 0, stream>>>(WO, WOt, E_, E_);
  wconvT<<<dim3(128, 32), 256, 0, stream>>>(W1, W1t, E_, FF_);
  wconvT<<<dim3(32, 128), 256, 0, stream>>>(W2, W2t, FF_, E_);
  bpack<<<12, 256, 0, stream>>>(bQ, bK, bV, bqkv);

  rmsnorm_kernel<<<M, 256, 0, stream>>>(x, g1, h1);

  gemm_bf16<1, 0, 0><<<dim3(24, 64), 256, 0, stream>>>(h1, WQKVt, bqkv, nullptr, QKV, M, 3072, E_);

  rope_kernel<<<(B_ * S_ * H_ * 32) / 256, 256, 0, stream>>>(QKV);

  vtrans<<<dim3(16, 128), 256, 0, stream>>>(QKV, Vt);

  attn_mfma<<<dim3(16, B_ * H_), 256, 0, stream>>>(QKV, Vt, Ob);

  gemm_bf16<0, 0, 1><<<dim3(8, 64), 256, 0, stream>>>(Ob, WOt, bO, x, x1, M, E_, E_);

  rmsnorm_kernel<<<M, 256, 0, stream>>>(x1, g2, h2);

  gemm_bf16<1, 1, 0><<<dim3(32, 64), 256, 0, stream>>>(h2, W1t, b1, nullptr, mid, M, FF_, E_);

  gemm_bf16<0, 0, 1><<<dim3(8, 64), 256, 0, stream>>>(mid, W2t, b2, x1, out, M, E_, FF_);
}

// Round 4
// 549.915 us; speedup vs baseline: 7.8752x; 1.1087x over previous
//
#include <hip/hip_runtime.h>
#include <math.h>

#define B_ 8
#define S_ 1024
#define E_ 1024
#define H_ 16
#define FF_ 4096

typedef __attribute__((ext_vector_type(8))) short bf16x8;
typedef __attribute__((ext_vector_type(4))) float f32x4;

__device__ __forceinline__ unsigned short f2bf(float f) {
  union { float f; unsigned u; } v;
  v.f = f;
  unsigned r = v.u + 0x7fffu + ((v.u >> 16) & 1u);
  return (unsigned short)(r >> 16);
}
__device__ __forceinline__ float bf2f(unsigned short u) {
  union { unsigned u; float f; } v;
  v.u = ((unsigned)u) << 16;
  return v.f;
}
__device__ __forceinline__ unsigned fbits(float f) {
  union { float f; unsigned u; } v;
  v.f = f;
  return v.u;
}

__device__ __forceinline__ void glds16(const void* g, void* l) {
  __builtin_amdgcn_global_load_lds(
      (const __attribute__((address_space(1))) unsigned int*)g,
      (__attribute__((address_space(3))) unsigned int*)l, 16, 0, 0);
}

// ---------------- weight convert+transpose: W[K][N] fp32 -> Wt[N][K] bf16 ----------------
__global__ __launch_bounds__(256) void wconvT(const float* __restrict__ W,
                                              unsigned short* __restrict__ Wt,
                                              int K, int N) {
  __shared__ float t[32][33];
  const int tx = threadIdx.x & 31, ty = threadIdx.x >> 5;
  const int n0 = blockIdx.x * 32, k0 = blockIdx.y * 32;
#pragma unroll
  for (int p = 0; p < 4; ++p)
    t[ty + p * 8][tx] = W[(size_t)(k0 + ty + p * 8) * N + n0 + tx];
  __syncthreads();
#pragma unroll
  for (int p = 0; p < 4; ++p)
    Wt[(size_t)(n0 + ty + p * 8) * K + k0 + tx] = f2bf(t[tx][ty + p * 8]);
}

// ---------------- pack QKV biases ----------------
__global__ __launch_bounds__(256) void bpack(const float* __restrict__ bQ,
                                             const float* __restrict__ bK,
                                             const float* __restrict__ bV,
                                             float* __restrict__ o) {
  const int i = blockIdx.x * 256 + threadIdx.x;
  const float v = (i < 1024) ? bQ[i] : ((i < 2048) ? bK[i - 1024] : bV[i - 2048]);
  o[i] = v;
}

// ---------------- RMSNorm: fp32 in, bf16 out; one block per row ----------------
__global__ __launch_bounds__(256) void rmsnorm_kernel(const float* __restrict__ x,
                                                      const float* __restrict__ g,
                                                      unsigned short* __restrict__ out) {
  const int row = blockIdx.x;
  const int t = threadIdx.x;
  const float4 v = ((const float4*)(x + (size_t)row * E_))[t];
  float ss = v.x * v.x + v.y * v.y + v.z * v.z + v.w * v.w;
#pragma unroll
  for (int off = 32; off > 0; off >>= 1) ss += __shfl_down(ss, off);
  __shared__ float sred[4];
  if ((t & 63) == 0) sred[t >> 6] = ss;
  __syncthreads();
  const float tot = sred[0] + sred[1] + sred[2] + sred[3];
  const float rinv = rsqrtf(tot * (1.0f / E_) + 1.1920929e-07f);
  const float4 gv = ((const float4*)g)[t];
  ushort4 o;
  o.x = f2bf(v.x * rinv * gv.x);
  o.y = f2bf(v.y * rinv * gv.y);
  o.z = f2bf(v.z * rinv * gv.z);
  o.w = f2bf(v.w * rinv * gv.w);
  ((ushort4*)(out + (size_t)row * E_))[t] = o;
}

// ---------------- bf16 MFMA GEMM: C[M,N] = A[M,K] @ Bt[N,K]^T, XCD-swizzled 1D grid ------
template <int OUT_BF16, int RELU, int RES>
__global__ __launch_bounds__(256) void gemm_bf16(const unsigned short* __restrict__ A,
                                                 const unsigned short* __restrict__ Bt,
                                                 const float* __restrict__ bias,
                                                 const float* __restrict__ res,
                                                 void* __restrict__ C,
                                                 int M, int N, int K) {
  __shared__ unsigned short As[128 * 32];
  __shared__ unsigned short Bs[128 * 32];
  const int tid = threadIdx.x;
  const int w = tid >> 6;
  const int lane = tid & 63;

  const int nb = gridDim.x;
  const int id = blockIdx.x;
  const int lid = (id & 7) * (nb >> 3) + (id >> 3);
  const int per = (M >> 7) * 8;
  const int grp = lid / per;
  const int rem = lid - grp * per;
  const int bn = (grp * 8 + (rem & 7)) * 128;
  const int bm = (rem >> 3) * 128;

  const int wm = (w & 1) * 64, wn = (w >> 1) * 64;

  f32x4 acc[4][4];
#pragma unroll
  for (int i = 0; i < 4; ++i)
#pragma unroll
    for (int j = 0; j < 4; ++j) acc[i][j] = (f32x4){0.f, 0.f, 0.f, 0.f};

  const unsigned short* Ap0 = A + (size_t)(bm + w * 32 + (lane >> 2)) * K + (lane & 3) * 8;
  const unsigned short* Ap1 = Ap0 + (size_t)16 * K;
  const unsigned short* Bp0 = Bt + (size_t)(bn + w * 32 + (lane >> 2)) * K + (lane & 3) * 8;
  const unsigned short* Bp1 = Bp0 + (size_t)16 * K;
  unsigned short* AsD0 = &As[w * 1024];
  unsigned short* AsD1 = AsD0 + 512;
  unsigned short* BsD0 = &Bs[w * 1024];
  unsigned short* BsD1 = BsD0 + 512;

  const int fr = lane & 15;
  const int fk = (lane >> 4) * 8;

  for (int k0 = 0; k0 < K; k0 += 32) {
    __syncthreads();
    glds16(Ap0 + k0, AsD0);
    glds16(Ap1 + k0, AsD1);
    glds16(Bp0 + k0, BsD0);
    glds16(Bp1 + k0, BsD1);
    __syncthreads();
    bf16x8 a[4], b[4];
#pragma unroll
    for (int im = 0; im < 4; ++im)
      a[im] = *(const bf16x8*)&As[(wm + im * 16 + fr) * 32 + fk];
#pragma unroll
    for (int in = 0; in < 4; ++in)
      b[in] = *(const bf16x8*)&Bs[(wn + in * 16 + fr) * 32 + fk];
#pragma unroll
    for (int im = 0; im < 4; ++im)
#pragma unroll
      for (int in = 0; in < 4; ++in)
        acc[im][in] = __builtin_amdgcn_mfma_f32_16x16x32_bf16(a[im], b[in], acc[im][in], 0, 0, 0);
  }

#pragma unroll
  for (int im = 0; im < 4; ++im) {
    const int row0 = bm + wm + im * 16 + (lane >> 4) * 4;
#pragma unroll
    for (int in = 0; in < 4; ++in) {
      const int col = bn + wn + in * 16 + (lane & 15);
      const float bv = bias[col];
#pragma unroll
      for (int r = 0; r < 4; ++r) {
        float v = acc[im][in][r] + bv;
        if (RES) v += res[(size_t)(row0 + r) * N + col];
        if (RELU) v = fmaxf(v, 0.0f);
        if (OUT_BF16)
          ((unsigned short*)C)[(size_t)(row0 + r) * N + col] = f2bf(v);
        else
          ((float*)C)[(size_t)(row0 + r) * N + col] = v;
      }
    }
  }
}

// ---------------- RoPE on fused QKV (stride 3072); Q pre-scaled by 0.125*log2e ----------
#define QSCALE 0.1803368801111f
__global__ __launch_bounds__(256) void rope_kernel(unsigned short* __restrict__ QKV) {
  const int i = blockIdx.x * 256 + threadIdx.x;
  const int fi = i & 31;
  const int h = (i >> 5) & 15;
  const int bs = i >> 9;
  const int s = bs & (S_ - 1);
  const float inv = exp2f(-0.4152410118f * (float)fi);  // 10000^(-fi/32)
  const float ang = (float)s * inv;
  const float cs = __cosf(ang), sn = __sinf(ang);
  const size_t base = (size_t)bs * 3072 + h * 64 + fi;
  const float q1 = bf2f(QKV[base]), q2 = bf2f(QKV[base + 32]);
  QKV[base] = f2bf((q1 * cs - q2 * sn) * QSCALE);
  QKV[base + 32] = f2bf((q2 * cs + q1 * sn) * QSCALE);
  const size_t kb = base + 1024;
  const float k1 = bf2f(QKV[kb]), k2 = bf2f(QKV[kb + 32]);
  QKV[kb] = f2bf(k1 * cs - k2 * sn);
  QKV[kb + 32] = f2bf(k2 * cs + k1 * sn);
}

// ---------------- V transpose: QKV V-cols -> Vt[(b*16+h)*64 + d][s] ----------------
__global__ __launch_bounds__(256) void vtrans(const unsigned short* __restrict__ QKV,
                                              unsigned short* __restrict__ Vt) {
  __shared__ unsigned short T[64 * 66];
  const int tid = threadIdx.x;
  const int st = blockIdx.x, bh = blockIdx.y;
  const int b = bh >> 4, h = bh & 15;
  const int sx = tid & 15, sy = tid >> 4;
#pragma unroll
  for (int p = 0; p < 4; ++p) {
    const int sl = p * 16 + sy;
    const ushort4 v = *(const ushort4*)&QKV[(size_t)(b * S_ + st * 64 + sl) * 3072 + 2048 + h * 64 + sx * 4];
    *(ushort4*)&T[sl * 66 + sx * 4] = v;
  }
  __syncthreads();
#pragma unroll
  for (int p = 0; p < 4; ++p) {
    const int dl = p * 16 + sy;
    ushort4 o;
    o.x = T[(sx * 4 + 0) * 66 + dl];
    o.y = T[(sx * 4 + 1) * 66 + dl];
    o.z = T[(sx * 4 + 2) * 66 + dl];
    o.w = T[(sx * 4 + 3) * 66 + dl];
    *(ushort4*)&Vt[(size_t)(bh * 64 + dl) * S_ + st * 64 + sx * 4] = o;
  }
}

// ---------------- MFMA flash attention v3: S^T form, 128 q/block, 32 q/wave --------------
__global__ __launch_bounds__(256) void attn_v3(const unsigned short* __restrict__ QKV,
                                               const unsigned short* __restrict__ Vt,
                                               unsigned short* __restrict__ Og) {
  __shared__ unsigned short Kf[8 * 512];
  __shared__ unsigned short Vf[8 * 512];
  __shared__ unsigned short Ps[4][32 * 72];
  const int tid = threadIdx.x;
  const int w = tid >> 6, lane = tid & 63;
  const int qt = blockIdx.x, bh = blockIdx.y;
  const int b = bh >> 4, h = bh & 15;
  const int fr = lane & 15, g = lane >> 4, fk = g * 8;
  const int q0w = qt * 128 + w * 32;

  bf16x8 qB[2][2];
#pragma unroll
  for (int nt = 0; nt < 2; ++nt)
#pragma unroll
    for (int c = 0; c < 2; ++c)
      qB[nt][c] = *(const bf16x8*)&QKV[(size_t)(b * S_ + q0w + nt * 16 + fr) * 3072 +
                                       h * 64 + c * 32 + fk];

  f32x4 o[4][2];
#pragma unroll
  for (int mt = 0; mt < 4; ++mt)
#pragma unroll
    for (int nt = 0; nt < 2; ++nt) o[mt][nt] = (f32x4){0.f, 0.f, 0.f, 0.f};
  float l[2] = {0.0f, 0.0f};

  for (int kt = 0; kt < 16; ++kt) {
    __syncthreads();
#pragma unroll
    for (int p = 0; p < 4; ++p) {
      const int u = w * 4 + p;
      if (u < 8) {
        const int mt = u >> 1, c = u & 1;
        glds16(QKV + (size_t)(b * S_ + kt * 64 + mt * 16 + fr) * 3072 +
                   1024 + h * 64 + c * 32 + fk,
               &Kf[u * 512]);
      } else {
        const int v = u - 8, mt = v >> 1, c = v & 1;
        glds16(Vt + (size_t)(bh * 64 + mt * 16 + fr) * S_ + kt * 64 + c * 32 + fk,
               &Vf[v * 512]);
      }
    }
    __syncthreads();

    f32x4 s[4][2];
#pragma unroll
    for (int mt = 0; mt < 4; ++mt) {
      const bf16x8 k0 = *(const bf16x8*)&Kf[(mt * 2 + 0) * 512 + lane * 8];
      const bf16x8 k1 = *(const bf16x8*)&Kf[(mt * 2 + 1) * 512 + lane * 8];
#pragma unroll
      for (int nt = 0; nt < 2; ++nt) {
        f32x4 a = (f32x4){0.f, 0.f, 0.f, 0.f};
        a = __builtin_amdgcn_mfma_f32_16x16x32_bf16(k0, qB[nt][0], a, 0, 0, 0);
        a = __builtin_amdgcn_mfma_f32_16x16x32_bf16(k1, qB[nt][1], a, 0, 0, 0);
        s[mt][nt] = a;
      }
    }

#pragma unroll
    for (int nt = 0; nt < 2; ++nt) {
      float rs = 0.0f;
#pragma unroll
      for (int mt = 0; mt < 4; ++mt)
#pragma unroll
        for (int r = 0; r < 4; ++r) {
          const float p = exp2f(s[mt][nt][r]);
          s[mt][nt][r] = p;
          rs += p;
        }
      rs += __shfl_xor(rs, 16);
      rs += __shfl_xor(rs, 32);
      l[nt] += rs;
    }

#pragma unroll
    for (int nt = 0; nt < 2; ++nt)
#pragma unroll
      for (int mt = 0; mt < 4; ++mt) {
        uint2 pk;
        pk.x = __builtin_amdgcn_perm(fbits(s[mt][nt][1]), fbits(s[mt][nt][0]), 0x07060302u);
        pk.y = __builtin_amdgcn_perm(fbits(s[mt][nt][3]), fbits(s[mt][nt][2]), 0x07060302u);
        *(uint2*)&Ps[w][(nt * 16 + fr) * 72 + mt * 16 + g * 4] = pk;
      }

    bf16x8 pB[2][2];
#pragma unroll
    for (int nt = 0; nt < 2; ++nt)
#pragma unroll
      for (int c = 0; c < 2; ++c)
        pB[nt][c] = *(const bf16x8*)&Ps[w][(nt * 16 + fr) * 72 + c * 32 + fk];
#pragma unroll
    for (int mt = 0; mt < 4; ++mt) {
      const bf16x8 v0 = *(const bf16x8*)&Vf[(mt * 2 + 0) * 512 + lane * 8];
      const bf16x8 v1 = *(const bf16x8*)&Vf[(mt * 2 + 1) * 512 + lane * 8];
#pragma unroll
      for (int nt = 0; nt < 2; ++nt) {
        o[mt][nt] = __builtin_amdgcn_mfma_f32_16x16x32_bf16(v0, pB[nt][0], o[mt][nt], 0, 0, 0);
        o[mt][nt] = __builtin_amdgcn_mfma_f32_16x16x32_bf16(v1, pB[nt][1], o[mt][nt], 0, 0, 0);
      }
    }
  }

  __syncthreads();
  const float linv0 = 1.0f / l[0], linv1 = 1.0f / l[1];
#pragma unroll
  for (int nt = 0; nt < 2; ++nt) {
    const float li = nt ? linv1 : linv0;
#pragma unroll
    for (int mt = 0; mt < 4; ++mt) {
      uint2 pk;
      pk.x = __builtin_amdgcn_perm(fbits(o[mt][nt][1] * li), fbits(o[mt][nt][0] * li), 0x07060302u);
      pk.y = __builtin_amdgcn_perm(fbits(o[mt][nt][3] * li), fbits(o[mt][nt][2] * li), 0x07060302u);
      *(uint2*)&Ps[w][(nt * 16 + fr) * 72 + mt * 16 + g * 4] = pk;
    }
  }
  __syncthreads();
  const int qr = lane >> 1, hf = lane & 1;
#pragma unroll
  for (int c = 0; c < 2; ++c) {
    const bf16x8 vv = *(const bf16x8*)&Ps[w][qr * 72 + hf * 16 + c * 32];
    *(bf16x8*)&Og[(size_t)(b * S_ + q0w + qr) * E_ + h * 64 + hf * 16 + c * 32] = vv;
  }
}

extern "C" void kernel_launch(void* const* d_in, const int* in_sizes, int n_in,
                              void* d_out, int out_size, void* d_ws, size_t ws_size,
                              hipStream_t stream) {
  const float* x  = (const float*)d_in[0];
  const float* WQ = (const float*)d_in[1];
  const float* bQ = (const float*)d_in[2];
  const float* WK = (const float*)d_in[3];
  const float* bK = (const float*)d_in[4];
  const float* WV = (const float*)d_in[5];
  const float* bV = (const float*)d_in[6];
  const float* WO = (const float*)d_in[7];
  const float* bO = (const float*)d_in[8];
  const float* W1 = (const float*)d_in[9];
  const float* b1 = (const float*)d_in[10];
  const float* W2 = (const float*)d_in[11];
  const float* b2 = (const float*)d_in[12];
  const float* g1 = (const float*)d_in[13];
  const float* g2 = (const float*)d_in[14];
  float* out = (float*)d_out;

  char* ws = (char*)d_ws;
  const size_t MB = 1024 * 1024;
  unsigned short* h1   = (unsigned short*)(ws + 0 * MB);
  unsigned short* QKV  = (unsigned short*)(ws + 16 * MB);
  unsigned short* Vt   = (unsigned short*)(ws + 64 * MB);
  unsigned short* Ob   = (unsigned short*)(ws + 80 * MB);
  float*          x1   = (float*)(ws + 96 * MB);
  unsigned short* h2   = (unsigned short*)(ws + 128 * MB);
  unsigned short* mid  = (unsigned short*)(ws + 16 * MB);
  unsigned short* WQKVt= (unsigned short*)(ws + 144 * MB);
  unsigned short* WOt  = (unsigned short*)(ws + 150 * MB);
  unsigned short* W1t  = (unsigned short*)(ws + 152 * MB);
  unsigned short* W2t  = (unsigned short*)(ws + 160 * MB);
  float*          bqkv = (float*)(ws + 168 * MB);

  const int M = B_ * S_;

  wconvT<<<dim3(32, 32), 256, 0, stream>>>(WQ, WQKVt, E_, E_);
  wconvT<<<dim3(32, 32), 256, 0, stream>>>(WK, WQKVt + 1024 * 1024, E_, E_);
  wconvT<<<dim3(32, 32), 256, 0, stream>>>(WV, WQKVt + 2 * 1024 * 1024, E_, E_);
  wconvT<<<dim3(32, 32), 256, 0, stream>>>(WO, WOt, E_, E_);
  wconvT<<<dim3(128, 32), 256, 0, stream>>>(W1, W1t, E_, FF_);
  wconvT<<<dim3(32, 128), 256, 0, stream>>>(W2, W2t, FF_, E_);
  bpack<<<12, 256, 0, stream>>>(bQ, bK, bV, bqkv);

  rmsnorm_kernel<<<M, 256, 0, stream>>>(x, g1, h1);

  gemm_bf16<1, 0, 0><<<24 * 64, 256, 0, stream>>>(h1, WQKVt, bqkv, nullptr, QKV, M, 3072, E_);

  rope_kernel<<<(B_ * S_ * H_ * 32) / 256, 256, 0, stream>>>(QKV);

  vtrans<<<dim3(16, 128), 256, 0, stream>>>(QKV, Vt);

  attn_v3<<<dim3(8, B_ * H_), 256, 0, stream>>>(QKV, Vt, Ob);

  gemm_bf16<0, 0, 1><<<8 * 64, 256, 0, stream>>>(Ob, WOt, bO, x, x1, M, E_, E_);

  rmsnorm_kernel<<<M, 256, 0, stream>>>(x1, g2, h2);

  gemm_bf16<1, 1, 0><<<32 * 64, 256, 0, stream>>>(h2, W1t, b1, nullptr, mid, M, FF_, E_);

  gemm_bf16<0, 0, 1><<<8 * 64, 256, 0, stream>>>(mid, W2t, b2, x1, out, M, E_, FF_);
}

// Round 5
// 542.766 us; speedup vs baseline: 7.9789x; 1.0132x over previous
//
#include <hip/hip_runtime.h>
#include <math.h>

#define B_ 8
#define S_ 1024
#define E_ 1024
#define H_ 16
#define FF_ 4096

typedef __attribute__((ext_vector_type(8))) short bf16x8;
typedef __attribute__((ext_vector_type(4))) float f32x4;

#define QSCALE 0.1803368801111f  // 0.125 * log2(e)
#define LG2_10K 0.4152410118f    // log2(10000)/32

__device__ __forceinline__ unsigned short f2bf(float f) {
  union { float f; unsigned u; } v;
  v.f = f;
  unsigned r = v.u + 0x7fffu + ((v.u >> 16) & 1u);
  return (unsigned short)(r >> 16);
}
__device__ __forceinline__ float bf2f(unsigned short u) {
  union { unsigned u; float f; } v;
  v.u = ((unsigned)u) << 16;
  return v.f;
}
__device__ __forceinline__ unsigned fbits(float f) {
  union { float f; unsigned u; } v;
  v.f = f;
  return v.u;
}

__device__ __forceinline__ void glds16(const void* g, void* l) {
  __builtin_amdgcn_global_load_lds(
      (const __attribute__((address_space(1))) unsigned int*)g,
      (__attribute__((address_space(3))) unsigned int*)l, 16, 0, 0);
}

// ---------------- weight convert+transpose: W[K][N] fp32 -> Wt[N][K] bf16 ----------------
__global__ __launch_bounds__(256) void wconvT(const float* __restrict__ W,
                                              unsigned short* __restrict__ Wt,
                                              int K, int N) {
  __shared__ float t[32][33];
  const int tx = threadIdx.x & 31, ty = threadIdx.x >> 5;
  const int n0 = blockIdx.x * 32, k0 = blockIdx.y * 32;
#pragma unroll
  for (int p = 0; p < 4; ++p)
    t[ty + p * 8][tx] = W[(size_t)(k0 + ty + p * 8) * N + n0 + tx];
  __syncthreads();
#pragma unroll
  for (int p = 0; p < 4; ++p)
    Wt[(size_t)(n0 + ty + p * 8) * K + k0 + tx] = f2bf(t[tx][ty + p * 8]);
}

// ---------------- pack QKV biases ----------------
__global__ __launch_bounds__(256) void bpack(const float* __restrict__ bQ,
                                             const float* __restrict__ bK,
                                             const float* __restrict__ bV,
                                             float* __restrict__ o) {
  const int i = blockIdx.x * 256 + threadIdx.x;
  const float v = (i < 1024) ? bQ[i] : ((i < 2048) ? bK[i - 1024] : bV[i - 2048]);
  o[i] = v;
}

// ---------------- RMSNorm: fp32 in, bf16 out; one block per row ----------------
__global__ __launch_bounds__(256) void rmsnorm_kernel(const float* __restrict__ x,
                                                      const float* __restrict__ g,
                                                      unsigned short* __restrict__ out) {
  const int row = blockIdx.x;
  const int t = threadIdx.x;
  const float4 v = ((const float4*)(x + (size_t)row * E_))[t];
  float ss = v.x * v.x + v.y * v.y + v.z * v.z + v.w * v.w;
#pragma unroll
  for (int off = 32; off > 0; off >>= 1) ss += __shfl_down(ss, off);
  __shared__ float sred[4];
  if ((t & 63) == 0) sred[t >> 6] = ss;
  __syncthreads();
  const float tot = sred[0] + sred[1] + sred[2] + sred[3];
  const float rinv = rsqrtf(tot * (1.0f / E_) + 1.1920929e-07f);
  const float4 gv = ((const float4*)g)[t];
  ushort4 o;
  o.x = f2bf(v.x * rinv * gv.x);
  o.y = f2bf(v.y * rinv * gv.y);
  o.z = f2bf(v.z * rinv * gv.z);
  o.w = f2bf(v.w * rinv * gv.w);
  ((ushort4*)(out + (size_t)row * E_))[t] = o;
}

// ---------------- bf16 MFMA GEMM 128x128 (m97 pattern), XCD-swizzled 1D grid ------------
template <int OUT_BF16, int RELU, int RES>
__global__ __launch_bounds__(256) void gemm_bf16(const unsigned short* __restrict__ A,
                                                 const unsigned short* __restrict__ Bt,
                                                 const float* __restrict__ bias,
                                                 const float* __restrict__ res,
                                                 void* __restrict__ C,
                                                 int M, int N, int K) {
  __shared__ unsigned short As[128 * 32];
  __shared__ unsigned short Bs[128 * 32];
  const int tid = threadIdx.x;
  const int w = tid >> 6;
  const int lane = tid & 63;

  const int nb = gridDim.x;
  const int id = blockIdx.x;
  const int lid = (id & 7) * (nb >> 3) + (id >> 3);
  const int per = (M >> 7) * 8;
  const int grp = lid / per;
  const int rem = lid - grp * per;
  const int bn = (grp * 8 + (rem & 7)) * 128;
  const int bm = (rem >> 3) * 128;

  const int wm = (w & 1) * 64, wn = (w >> 1) * 64;

  f32x4 acc[4][4];
#pragma unroll
  for (int i = 0; i < 4; ++i)
#pragma unroll
    for (int j = 0; j < 4; ++j) acc[i][j] = (f32x4){0.f, 0.f, 0.f, 0.f};

  const unsigned short* Ap0 = A + (size_t)(bm + w * 32 + (lane >> 2)) * K + (lane & 3) * 8;
  const unsigned short* Ap1 = Ap0 + (size_t)16 * K;
  const unsigned short* Bp0 = Bt + (size_t)(bn + w * 32 + (lane >> 2)) * K + (lane & 3) * 8;
  const unsigned short* Bp1 = Bp0 + (size_t)16 * K;
  unsigned short* AsD0 = &As[w * 1024];
  unsigned short* AsD1 = AsD0 + 512;
  unsigned short* BsD0 = &Bs[w * 1024];
  unsigned short* BsD1 = BsD0 + 512;

  const int fr = lane & 15;
  const int fk = (lane >> 4) * 8;

  for (int k0 = 0; k0 < K; k0 += 32) {
    __syncthreads();
    glds16(Ap0 + k0, AsD0);
    glds16(Ap1 + k0, AsD1);
    glds16(Bp0 + k0, BsD0);
    glds16(Bp1 + k0, BsD1);
    __syncthreads();
    bf16x8 a[4], b[4];
#pragma unroll
    for (int im = 0; im < 4; ++im)
      a[im] = *(const bf16x8*)&As[(wm + im * 16 + fr) * 32 + fk];
#pragma unroll
    for (int in = 0; in < 4; ++in)
      b[in] = *(const bf16x8*)&Bs[(wn + in * 16 + fr) * 32 + fk];
#pragma unroll
    for (int im = 0; im < 4; ++im)
#pragma unroll
      for (int in = 0; in < 4; ++in)
        acc[im][in] = __builtin_amdgcn_mfma_f32_16x16x32_bf16(a[im], b[in], acc[im][in], 0, 0, 0);
  }

#pragma unroll
  for (int im = 0; im < 4; ++im) {
    const int row0 = bm + wm + im * 16 + (lane >> 4) * 4;
#pragma unroll
    for (int in = 0; in < 4; ++in) {
      const int col = bn + wn + in * 16 + (lane & 15);
      const float bv = bias[col];
#pragma unroll
      for (int r = 0; r < 4; ++r) {
        float v = acc[im][in][r] + bv;
        if (RES) v += res[(size_t)(row0 + r) * N + col];
        if (RELU) v = fmaxf(v, 0.0f);
        if (OUT_BF16)
          ((unsigned short*)C)[(size_t)(row0 + r) * N + col] = f2bf(v);
        else
          ((float*)C)[(size_t)(row0 + r) * N + col] = v;
      }
    }
  }
}

// ---------------- bf16 MFMA GEMM 128x64 tile (for low-N GEMMs: more blocks/CU) ----------
template <int OUT_BF16, int RELU, int RES>
__global__ __launch_bounds__(256) void gemm_n64(const unsigned short* __restrict__ A,
                                                const unsigned short* __restrict__ Bt,
                                                const float* __restrict__ bias,
                                                const float* __restrict__ res,
                                                void* __restrict__ C,
                                                int M, int N, int K) {
  __shared__ unsigned short As[128 * 32];
  __shared__ unsigned short Bs[64 * 32];
  const int tid = threadIdx.x;
  const int w = tid >> 6;
  const int lane = tid & 63;

  const int nbn = N >> 6;
  const int bm = (blockIdx.x / nbn) * 128;
  const int bn = (blockIdx.x % nbn) * 64;

  const int wm = (w & 1) * 64, wn = (w >> 1) * 32;

  f32x4 acc[4][2];
#pragma unroll
  for (int i = 0; i < 4; ++i)
#pragma unroll
    for (int j = 0; j < 2; ++j) acc[i][j] = (f32x4){0.f, 0.f, 0.f, 0.f};

  const unsigned short* Ap0 = A + (size_t)(bm + w * 32 + (lane >> 2)) * K + (lane & 3) * 8;
  const unsigned short* Ap1 = Ap0 + (size_t)16 * K;
  const unsigned short* Bp0 = Bt + (size_t)(bn + w * 16 + (lane >> 2)) * K + (lane & 3) * 8;
  unsigned short* AsD0 = &As[w * 1024];
  unsigned short* AsD1 = AsD0 + 512;
  unsigned short* BsD0 = &Bs[w * 512];

  const int fr = lane & 15;
  const int fk = (lane >> 4) * 8;

  for (int k0 = 0; k0 < K; k0 += 32) {
    __syncthreads();
    glds16(Ap0 + k0, AsD0);
    glds16(Ap1 + k0, AsD1);
    glds16(Bp0 + k0, BsD0);
    __syncthreads();
    bf16x8 a[4], b[2];
#pragma unroll
    for (int im = 0; im < 4; ++im)
      a[im] = *(const bf16x8*)&As[(wm + im * 16 + fr) * 32 + fk];
#pragma unroll
    for (int in = 0; in < 2; ++in)
      b[in] = *(const bf16x8*)&Bs[(wn + in * 16 + fr) * 32 + fk];
#pragma unroll
    for (int im = 0; im < 4; ++im)
#pragma unroll
      for (int in = 0; in < 2; ++in)
        acc[im][in] = __builtin_amdgcn_mfma_f32_16x16x32_bf16(a[im], b[in], acc[im][in], 0, 0, 0);
  }

#pragma unroll
  for (int im = 0; im < 4; ++im) {
    const int row0 = bm + wm + im * 16 + (lane >> 4) * 4;
#pragma unroll
    for (int in = 0; in < 2; ++in) {
      const int col = bn + wn + in * 16 + fr;
      const float bv = bias[col];
#pragma unroll
      for (int r = 0; r < 4; ++r) {
        float v = acc[im][in][r] + bv;
        if (RES) v += res[(size_t)(row0 + r) * N + col];
        if (RELU) v = fmaxf(v, 0.0f);
        if (OUT_BF16)
          ((unsigned short*)C)[(size_t)(row0 + r) * N + col] = f2bf(v);
        else
          ((float*)C)[(size_t)(row0 + r) * N + col] = v;
      }
    }
  }
}

// ---------------- QKV GEMM with fused RoPE (Q,K) + transposed V store ------------------
// N = 3072. Each 64-col wave tile = exactly one head of Q, K, or V.
// Q/K: rotate-half RoPE in-register (pairs are the thread's own (in,in+2) accumulators);
// Q additionally scaled by 0.125*log2e. V: stored transposed to Vt[(b*16+h)*64+d][s].
__global__ __launch_bounds__(256) void gemm_qkv(const unsigned short* __restrict__ A,
                                                const unsigned short* __restrict__ Bt,
                                                const float* __restrict__ bias,
                                                unsigned short* __restrict__ QKV,
                                                unsigned short* __restrict__ Vt,
                                                int M, int K) {
  const int N = 3072;
  __shared__ unsigned short As[128 * 32];
  __shared__ unsigned short Bs[128 * 32];
  const int tid = threadIdx.x;
  const int w = tid >> 6;
  const int lane = tid & 63;

  const int nb = gridDim.x;
  const int id = blockIdx.x;
  const int lid = (id & 7) * (nb >> 3) + (id >> 3);
  const int per = (M >> 7) * 8;
  const int grp = lid / per;
  const int rem = lid - grp * per;
  const int bn = (grp * 8 + (rem & 7)) * 128;
  const int bm = (rem >> 3) * 128;

  const int wm = (w & 1) * 64, wn = (w >> 1) * 64;

  f32x4 acc[4][4];
#pragma unroll
  for (int i = 0; i < 4; ++i)
#pragma unroll
    for (int j = 0; j < 4; ++j) acc[i][j] = (f32x4){0.f, 0.f, 0.f, 0.f};

  const unsigned short* Ap0 = A + (size_t)(bm + w * 32 + (lane >> 2)) * K + (lane & 3) * 8;
  const unsigned short* Ap1 = Ap0 + (size_t)16 * K;
  const unsigned short* Bp0 = Bt + (size_t)(bn + w * 32 + (lane >> 2)) * K + (lane & 3) * 8;
  const unsigned short* Bp1 = Bp0 + (size_t)16 * K;
  unsigned short* AsD0 = &As[w * 1024];
  unsigned short* AsD1 = AsD0 + 512;
  unsigned short* BsD0 = &Bs[w * 1024];
  unsigned short* BsD1 = BsD0 + 512;

  const int fr = lane & 15;
  const int fk = (lane >> 4) * 8;

  for (int k0 = 0; k0 < K; k0 += 32) {
    __syncthreads();
    glds16(Ap0 + k0, AsD0);
    glds16(Ap1 + k0, AsD1);
    glds16(Bp0 + k0, BsD0);
    glds16(Bp1 + k0, BsD1);
    __syncthreads();
    bf16x8 a[4], b[4];
#pragma unroll
    for (int im = 0; im < 4; ++im)
      a[im] = *(const bf16x8*)&As[(wm + im * 16 + fr) * 32 + fk];
#pragma unroll
    for (int in = 0; in < 4; ++in)
      b[in] = *(const bf16x8*)&Bs[(wn + in * 16 + fr) * 32 + fk];
#pragma unroll
    for (int im = 0; im < 4; ++im)
#pragma unroll
      for (int in = 0; in < 4; ++in)
        acc[im][in] = __builtin_amdgcn_mfma_f32_16x16x32_bf16(a[im], b[in], acc[im][in], 0, 0, 0);
  }

  const int cbase = bn + wn;
  const int seg = cbase >> 6;        // 0..47
  const int typ = seg >> 4;          // 0=Q, 1=K, 2=V
  const int hh = seg & 15;           // head
  const int bidx = bm >> 10;         // batch
  float bv[4];
#pragma unroll
  for (int in = 0; in < 4; ++in) bv[in] = bias[cbase + in * 16 + fr];

  if (typ == 2) {
    // V: store transposed, ushort4 over 4 consecutive s
#pragma unroll
    for (int im = 0; im < 4; ++im) {
      const int s0 = (bm & 1023) + wm + im * 16 + (lane >> 4) * 4;
#pragma unroll
      for (int in = 0; in < 4; ++in) {
        const int d = in * 16 + fr;
        ushort4 o4;
        o4.x = f2bf(acc[im][in][0] + bv[in]);
        o4.y = f2bf(acc[im][in][1] + bv[in]);
        o4.z = f2bf(acc[im][in][2] + bv[in]);
        o4.w = f2bf(acc[im][in][3] + bv[in]);
        *(ushort4*)&Vt[(size_t)((bidx * 16 + hh) * 64 + d) * S_ + s0] = o4;
      }
    }
  } else {
    const float qs = (typ == 0) ? QSCALE : 1.0f;
    const float i0 = exp2f(-LG2_10K * (float)fr);
    const float i1 = exp2f(-LG2_10K * (float)(fr + 16));
#pragma unroll
    for (int im = 0; im < 4; ++im) {
      const int row0 = bm + wm + im * 16 + (lane >> 4) * 4;
#pragma unroll
      for (int r = 0; r < 4; ++r) {
        const int row = row0 + r;
        const float s = (float)(row & 1023);
        float sn0, cs0, sn1, cs1;
        __sincosf(s * i0, &sn0, &cs0);
        __sincosf(s * i1, &sn1, &cs1);
        const float x0 = acc[im][0][r] + bv[0];
        const float x1 = acc[im][1][r] + bv[1];
        const float x2 = acc[im][2][r] + bv[2];
        const float x3 = acc[im][3][r] + bv[3];
        unsigned short* cp = QKV + (size_t)row * 3072 + cbase;
        cp[fr]      = f2bf((x0 * cs0 - x2 * sn0) * qs);
        cp[16 + fr] = f2bf((x1 * cs1 - x3 * sn1) * qs);
        cp[32 + fr] = f2bf((x2 * cs0 + x0 * sn0) * qs);
        cp[48 + fr] = f2bf((x3 * cs1 + x1 * sn1) * qs);
      }
    }
  }
}

// ---------------- MFMA flash attention v4: S^T form + double-buffered K/V staging -------
__global__ __launch_bounds__(256) void attn_v4(const unsigned short* __restrict__ QKV,
                                               const unsigned short* __restrict__ Vt,
                                               unsigned short* __restrict__ Og) {
  __shared__ unsigned short Kf[2][8 * 512];
  __shared__ unsigned short Vf[2][8 * 512];
  __shared__ unsigned short Ps[4][32 * 72];
  const int tid = threadIdx.x;
  const int w = tid >> 6, lane = tid & 63;
  const int qt = blockIdx.x, bh = blockIdx.y;
  const int b = bh >> 4, h = bh & 15;
  const int fr = lane & 15, g = lane >> 4, fk = g * 8;
  const int q0w = qt * 128 + w * 32;

  bf16x8 qB[2][2];
#pragma unroll
  for (int nt = 0; nt < 2; ++nt)
#pragma unroll
    for (int c = 0; c < 2; ++c)
      qB[nt][c] = *(const bf16x8*)&QKV[(size_t)(b * S_ + q0w + nt * 16 + fr) * 3072 +
                                       h * 64 + c * 32 + fk];

  f32x4 o[4][2];
#pragma unroll
  for (int mt = 0; mt < 4; ++mt)
#pragma unroll
    for (int nt = 0; nt < 2; ++nt) o[mt][nt] = (f32x4){0.f, 0.f, 0.f, 0.f};
  float l[2] = {0.0f, 0.0f};

  // stage k-tile kt into buffer bufi (4 glds per wave, fragment-major)
#define STAGE(kt, bufi)                                                                   \
  {                                                                                       \
    _Pragma("unroll") for (int p = 0; p < 4; ++p) {                                       \
      const int u = w * 4 + p;                                                            \
      if (u < 8) {                                                                        \
        const int mt = u >> 1, c = u & 1;                                                 \
        glds16(QKV + (size_t)(b * S_ + (kt) * 64 + mt * 16 + fr) * 3072 + 1024 + h * 64 + \
                   c * 32 + fk,                                                           \
               &Kf[bufi][u * 512]);                                                       \
      } else {                                                                            \
        const int v2 = u - 8, mt = v2 >> 1, c = v2 & 1;                                   \
        glds16(Vt + (size_t)(bh * 64 + mt * 16 + fr) * S_ + (kt) * 64 + c * 32 + fk,      \
               &Vf[bufi][v2 * 512]);                                                      \
      }                                                                                   \
    }                                                                                     \
  }

  STAGE(0, 0);

  for (int kt = 0; kt < 16; ++kt) {
    __syncthreads();  // drains in-flight glds: buf[kt&1] ready
    if (kt < 15) STAGE(kt + 1, (kt + 1) & 1);
    const unsigned short* Kc = Kf[kt & 1];
    const unsigned short* Vc = Vf[kt & 1];

    f32x4 s[4][2];
#pragma unroll
    for (int mt = 0; mt < 4; ++mt) {
      const bf16x8 k0 = *(const bf16x8*)&Kc[(mt * 2 + 0) * 512 + lane * 8];
      const bf16x8 k1 = *(const bf16x8*)&Kc[(mt * 2 + 1) * 512 + lane * 8];
#pragma unroll
      for (int nt = 0; nt < 2; ++nt) {
        f32x4 a = (f32x4){0.f, 0.f, 0.f, 0.f};
        a = __builtin_amdgcn_mfma_f32_16x16x32_bf16(k0, qB[nt][0], a, 0, 0, 0);
        a = __builtin_amdgcn_mfma_f32_16x16x32_bf16(k1, qB[nt][1], a, 0, 0, 0);
        s[mt][nt] = a;
      }
    }

#pragma unroll
    for (int nt = 0; nt < 2; ++nt) {
      float rs = 0.0f;
#pragma unroll
      for (int mt = 0; mt < 4; ++mt)
#pragma unroll
        for (int r = 0; r < 4; ++r) {
          const float p = exp2f(s[mt][nt][r]);
          s[mt][nt][r] = p;
          rs += p;
        }
      rs += __shfl_xor(rs, 16);
      rs += __shfl_xor(rs, 32);
      l[nt] += rs;
    }

#pragma unroll
    for (int nt = 0; nt < 2; ++nt)
#pragma unroll
      for (int mt = 0; mt < 4; ++mt) {
        uint2 pk;
        pk.x = __builtin_amdgcn_perm(fbits(s[mt][nt][1]), fbits(s[mt][nt][0]), 0x07060302u);
        pk.y = __builtin_amdgcn_perm(fbits(s[mt][nt][3]), fbits(s[mt][nt][2]), 0x07060302u);
        *(uint2*)&Ps[w][(nt * 16 + fr) * 72 + mt * 16 + g * 4] = pk;
      }

    bf16x8 pB[2][2];
#pragma unroll
    for (int nt = 0; nt < 2; ++nt)
#pragma unroll
      for (int c = 0; c < 2; ++c)
        pB[nt][c] = *(const bf16x8*)&Ps[w][(nt * 16 + fr) * 72 + c * 32 + fk];
#pragma unroll
    for (int mt = 0; mt < 4; ++mt) {
      const bf16x8 v0 = *(const bf16x8*)&Vc[(mt * 2 + 0) * 512 + lane * 8];
      const bf16x8 v1 = *(const bf16x8*)&Vc[(mt * 2 + 1) * 512 + lane * 8];
#pragma unroll
      for (int nt = 0; nt < 2; ++nt) {
        o[mt][nt] = __builtin_amdgcn_mfma_f32_16x16x32_bf16(v0, pB[nt][0], o[mt][nt], 0, 0, 0);
        o[mt][nt] = __builtin_amdgcn_mfma_f32_16x16x32_bf16(v1, pB[nt][1], o[mt][nt], 0, 0, 0);
      }
    }
  }

  // epilogue: Ps[w] is wave-private -> no barriers needed
  const float linv0 = 1.0f / l[0], linv1 = 1.0f / l[1];
#pragma unroll
  for (int nt = 0; nt < 2; ++nt) {
    const float li = nt ? linv1 : linv0;
#pragma unroll
    for (int mt = 0; mt < 4; ++mt) {
      uint2 pk;
      pk.x = __builtin_amdgcn_perm(fbits(o[mt][nt][1] * li), fbits(o[mt][nt][0] * li), 0x07060302u);
      pk.y = __builtin_amdgcn_perm(fbits(o[mt][nt][3] * li), fbits(o[mt][nt][2] * li), 0x07060302u);
      *(uint2*)&Ps[w][(nt * 16 + fr) * 72 + mt * 16 + g * 4] = pk;
    }
  }
  const int qr = lane >> 1, hf = lane & 1;
#pragma unroll
  for (int c = 0; c < 2; ++c) {
    const bf16x8 vv = *(const bf16x8*)&Ps[w][qr * 72 + hf * 16 + c * 32];
    *(bf16x8*)&Og[(size_t)(b * S_ + q0w + qr) * E_ + h * 64 + hf * 16 + c * 32] = vv;
  }
}

extern "C" void kernel_launch(void* const* d_in, const int* in_sizes, int n_in,
                              void* d_out, int out_size, void* d_ws, size_t ws_size,
                              hipStream_t stream) {
  const float* x  = (const float*)d_in[0];
  const float* WQ = (const float*)d_in[1];
  const float* bQ = (const float*)d_in[2];
  const float* WK = (const float*)d_in[3];
  const float* bK = (const float*)d_in[4];
  const float* WV = (const float*)d_in[5];
  const float* bV = (const float*)d_in[6];
  const float* WO = (const float*)d_in[7];
  const float* bO = (const float*)d_in[8];
  const float* W1 = (const float*)d_in[9];
  const float* b1 = (const float*)d_in[10];
  const float* W2 = (const float*)d_in[11];
  const float* b2 = (const float*)d_in[12];
  const float* g1 = (const float*)d_in[13];
  const float* g2 = (const float*)d_in[14];
  float* out = (float*)d_out;

  char* ws = (char*)d_ws;
  const size_t MB = 1024 * 1024;
  unsigned short* h1   = (unsigned short*)(ws + 0 * MB);
  unsigned short* QKV  = (unsigned short*)(ws + 16 * MB);   // [8192,3072]
  unsigned short* Vt   = (unsigned short*)(ws + 64 * MB);   // [128*64,1024]
  unsigned short* Ob   = (unsigned short*)(ws + 80 * MB);
  float*          x1   = (float*)(ws + 96 * MB);
  unsigned short* h2   = (unsigned short*)(ws + 128 * MB);
  unsigned short* mid  = (unsigned short*)(ws + 16 * MB);   // reuses QKV+Vt region
  unsigned short* WQKVt= (unsigned short*)(ws + 144 * MB);
  unsigned short* WOt  = (unsigned short*)(ws + 150 * MB);
  unsigned short* W1t  = (unsigned short*)(ws + 152 * MB);
  unsigned short* W2t  = (unsigned short*)(ws + 160 * MB);
  float*          bqkv = (float*)(ws + 168 * MB);

  const int M = B_ * S_;

  wconvT<<<dim3(32, 32), 256, 0, stream>>>(WQ, WQKVt, E_, E_);
  wconvT<<<dim3(32, 32), 256, 0, stream>>>(WK, WQKVt + 1024 * 1024, E_, E_);
  wconvT<<<dim3(32, 32), 256, 0, stream>>>(WV, WQKVt + 2 * 1024 * 1024, E_, E_);
  wconvT<<<dim3(32, 32), 256, 0, stream>>>(WO, WOt, E_, E_);
  wconvT<<<dim3(128, 32), 256, 0, stream>>>(W1, W1t, E_, FF_);
  wconvT<<<dim3(32, 128), 256, 0, stream>>>(W2, W2t, FF_, E_);
  bpack<<<12, 256, 0, stream>>>(bQ, bK, bV, bqkv);

  rmsnorm_kernel<<<M, 256, 0, stream>>>(x, g1, h1);

  // QKV + fused RoPE + V-transpose
  gemm_qkv<<<24 * 64, 256, 0, stream>>>(h1, WQKVt, bqkv, QKV, Vt, M, E_);

  attn_v4<<<dim3(8, B_ * H_), 256, 0, stream>>>(QKV, Vt, Ob);

  gemm_n64<0, 0, 1><<<64 * 16, 256, 0, stream>>>(Ob, WOt, bO, x, x1, M, E_, E_);

  rmsnorm_kernel<<<M, 256, 0, stream>>>(x1, g2, h2);

  gemm_bf16<1, 1, 0><<<32 * 64, 256, 0, stream>>>(h2, W1t, b1, nullptr, mid, M, FF_, E_);

  gemm_n64<0, 0, 1><<<64 * 16, 256, 0, stream>>>(mid, W2t, b2, x1, out, M, E_, FF_);
}

// Round 6
// 537.667 us; speedup vs baseline: 8.0546x; 1.0095x over previous
//
#include <hip/hip_runtime.h>
#include <math.h>

#define B_ 8
#define S_ 1024
#define E_ 1024
#define H_ 16
#define FF_ 4096

typedef __attribute__((ext_vector_type(8))) short bf16x8;
typedef __attribute__((ext_vector_type(4))) float f32x4;

#define QSCALE 0.1803368801111f  // 0.125 * log2(e)
#define LG2_10K 0.4152410118f    // log2(10000)/32

__device__ __forceinline__ unsigned short f2bf(float f) {
  union { float f; unsigned u; } v;
  v.f = f;
  unsigned r = v.u + 0x7fffu + ((v.u >> 16) & 1u);
  return (unsigned short)(r >> 16);
}
__device__ __forceinline__ float bf2f(unsigned short u) {
  union { unsigned u; float f; } v;
  v.u = ((unsigned)u) << 16;
  return v.f;
}
__device__ __forceinline__ unsigned fbits(float f) {
  union { float f; unsigned u; } v;
  v.f = f;
  return v.u;
}

__device__ __forceinline__ void glds16(const void* g, void* l) {
  __builtin_amdgcn_global_load_lds(
      (const __attribute__((address_space(1))) unsigned int*)g,
      (__attribute__((address_space(3))) unsigned int*)l, 16, 0, 0);
}

// ---------------- weight convert+transpose: W[K][N] fp32 -> Wt[N][K] bf16 ----------------
__global__ __launch_bounds__(256) void wconvT(const float* __restrict__ W,
                                              unsigned short* __restrict__ Wt,
                                              int K, int N) {
  __shared__ float t[32][33];
  const int tx = threadIdx.x & 31, ty = threadIdx.x >> 5;
  const int n0 = blockIdx.x * 32, k0 = blockIdx.y * 32;
#pragma unroll
  for (int p = 0; p < 4; ++p)
    t[ty + p * 8][tx] = W[(size_t)(k0 + ty + p * 8) * N + n0 + tx];
  __syncthreads();
#pragma unroll
  for (int p = 0; p < 4; ++p)
    Wt[(size_t)(n0 + ty + p * 8) * K + k0 + tx] = f2bf(t[tx][ty + p * 8]);
}

// four 1024x1024 converts in one launch (blockIdx.z selects matrix)
__global__ __launch_bounds__(256) void wconvT4(const float* __restrict__ W0,
                                               const float* __restrict__ W1p,
                                               const float* __restrict__ W2p,
                                               const float* __restrict__ W3p,
                                               unsigned short* __restrict__ D0,
                                               unsigned short* __restrict__ D1,
                                               unsigned short* __restrict__ D2,
                                               unsigned short* __restrict__ D3) {
  __shared__ float t[32][33];
  const int z = blockIdx.z;
  const float* W = (z == 0) ? W0 : (z == 1) ? W1p : (z == 2) ? W2p : W3p;
  unsigned short* D = (z == 0) ? D0 : (z == 1) ? D1 : (z == 2) ? D2 : D3;
  const int tx = threadIdx.x & 31, ty = threadIdx.x >> 5;
  const int n0 = blockIdx.x * 32, k0 = blockIdx.y * 32;
#pragma unroll
  for (int p = 0; p < 4; ++p)
    t[ty + p * 8][tx] = W[(size_t)(k0 + ty + p * 8) * E_ + n0 + tx];
  __syncthreads();
#pragma unroll
  for (int p = 0; p < 4; ++p)
    D[(size_t)(n0 + ty + p * 8) * E_ + k0 + tx] = f2bf(t[tx][ty + p * 8]);
}

// ---------------- pack QKV biases ----------------
__global__ __launch_bounds__(256) void bpack(const float* __restrict__ bQ,
                                             const float* __restrict__ bK,
                                             const float* __restrict__ bV,
                                             float* __restrict__ o) {
  const int i = blockIdx.x * 256 + threadIdx.x;
  const float v = (i < 1024) ? bQ[i] : ((i < 2048) ? bK[i - 1024] : bV[i - 2048]);
  o[i] = v;
}

// ---------------- RMSNorm: fp32 in, bf16 out; one block per row ----------------
__global__ __launch_bounds__(256) void rmsnorm_kernel(const float* __restrict__ x,
                                                      const float* __restrict__ g,
                                                      unsigned short* __restrict__ out) {
  const int row = blockIdx.x;
  const int t = threadIdx.x;
  const float4 v = ((const float4*)(x + (size_t)row * E_))[t];
  float ss = v.x * v.x + v.y * v.y + v.z * v.z + v.w * v.w;
#pragma unroll
  for (int off = 32; off > 0; off >>= 1) ss += __shfl_down(ss, off);
  __shared__ float sred[4];
  if ((t & 63) == 0) sred[t >> 6] = ss;
  __syncthreads();
  const float tot = sred[0] + sred[1] + sred[2] + sred[3];
  const float rinv = rsqrtf(tot * (1.0f / E_) + 1.1920929e-07f);
  const float4 gv = ((const float4*)g)[t];
  ushort4 o;
  o.x = f2bf(v.x * rinv * gv.x);
  o.y = f2bf(v.y * rinv * gv.y);
  o.z = f2bf(v.z * rinv * gv.z);
  o.w = f2bf(v.w * rinv * gv.w);
  ((ushort4*)(out + (size_t)row * E_))[t] = o;
}

// ---------------- bf16 MFMA GEMM 128x128 (m97 pattern), XCD-swizzled 1D grid ------------
template <int OUT_BF16, int RELU, int RES>
__global__ __launch_bounds__(256) void gemm_bf16(const unsigned short* __restrict__ A,
                                                 const unsigned short* __restrict__ Bt,
                                                 const float* __restrict__ bias,
                                                 const float* __restrict__ res,
                                                 void* __restrict__ C,
                                                 int M, int N, int K) {
  __shared__ unsigned short As[128 * 32];
  __shared__ unsigned short Bs[128 * 32];
  const int tid = threadIdx.x;
  const int w = tid >> 6;
  const int lane = tid & 63;

  const int nb = gridDim.x;
  const int id = blockIdx.x;
  const int lid = (id & 7) * (nb >> 3) + (id >> 3);
  const int per = (M >> 7) * 8;
  const int grp = lid / per;
  const int rem = lid - grp * per;
  const int bn = (grp * 8 + (rem & 7)) * 128;
  const int bm = (rem >> 3) * 128;

  const int wm = (w & 1) * 64, wn = (w >> 1) * 64;

  f32x4 acc[4][4];
#pragma unroll
  for (int i = 0; i < 4; ++i)
#pragma unroll
    for (int j = 0; j < 4; ++j) acc[i][j] = (f32x4){0.f, 0.f, 0.f, 0.f};

  const unsigned short* Ap0 = A + (size_t)(bm + w * 32 + (lane >> 2)) * K + (lane & 3) * 8;
  const unsigned short* Ap1 = Ap0 + (size_t)16 * K;
  const unsigned short* Bp0 = Bt + (size_t)(bn + w * 32 + (lane >> 2)) * K + (lane & 3) * 8;
  const unsigned short* Bp1 = Bp0 + (size_t)16 * K;
  unsigned short* AsD0 = &As[w * 1024];
  unsigned short* AsD1 = AsD0 + 512;
  unsigned short* BsD0 = &Bs[w * 1024];
  unsigned short* BsD1 = BsD0 + 512;

  const int fr = lane & 15;
  const int fk = (lane >> 4) * 8;

  for (int k0 = 0; k0 < K; k0 += 32) {
    __syncthreads();
    glds16(Ap0 + k0, AsD0);
    glds16(Ap1 + k0, AsD1);
    glds16(Bp0 + k0, BsD0);
    glds16(Bp1 + k0, BsD1);
    __syncthreads();
    bf16x8 a[4], b[4];
#pragma unroll
    for (int im = 0; im < 4; ++im)
      a[im] = *(const bf16x8*)&As[(wm + im * 16 + fr) * 32 + fk];
#pragma unroll
    for (int in = 0; in < 4; ++in)
      b[in] = *(const bf16x8*)&Bs[(wn + in * 16 + fr) * 32 + fk];
#pragma unroll
    for (int im = 0; im < 4; ++im)
#pragma unroll
      for (int in = 0; in < 4; ++in)
        acc[im][in] = __builtin_amdgcn_mfma_f32_16x16x32_bf16(a[im], b[in], acc[im][in], 0, 0, 0);
  }

#pragma unroll
  for (int im = 0; im < 4; ++im) {
    const int row0 = bm + wm + im * 16 + (lane >> 4) * 4;
#pragma unroll
    for (int in = 0; in < 4; ++in) {
      const int col = bn + wn + in * 16 + (lane & 15);
      const float bv = bias[col];
#pragma unroll
      for (int r = 0; r < 4; ++r) {
        float v = acc[im][in][r] + bv;
        if (RES) v += res[(size_t)(row0 + r) * N + col];
        if (RELU) v = fmaxf(v, 0.0f);
        if (OUT_BF16)
          ((unsigned short*)C)[(size_t)(row0 + r) * N + col] = f2bf(v);
        else
          ((float*)C)[(size_t)(row0 + r) * N + col] = v;
      }
    }
  }
}

// ---------------- split-K=2 GEMM for FF2: M=8192, N=1024, K=4096, 128x128 tile ----------
// grid = 1024: id<512 -> k-half 0, else half 1. Partials bf16 to Pp[kh][M][N].
__global__ __launch_bounds__(256) void gemm_sk2(const unsigned short* __restrict__ A,
                                                const unsigned short* __restrict__ Bt,
                                                unsigned short* __restrict__ Pp) {
  const int N = 1024, K = 4096, KH = 2048;
  __shared__ unsigned short As[128 * 32];
  __shared__ unsigned short Bs[128 * 32];
  const int tid = threadIdx.x;
  const int w = tid >> 6;
  const int lane = tid & 63;

  const int id = blockIdx.x;
  const int kh = id >> 9;
  const int hid = id & 511;
  const int lid = (hid & 7) * 64 + (hid >> 3);
  const int bn = (lid & 7) * 128;
  const int bm = (lid >> 3) * 128;

  const int wm = (w & 1) * 64, wn = (w >> 1) * 64;

  f32x4 acc[4][4];
#pragma unroll
  for (int i = 0; i < 4; ++i)
#pragma unroll
    for (int j = 0; j < 4; ++j) acc[i][j] = (f32x4){0.f, 0.f, 0.f, 0.f};

  const unsigned short* Ap0 =
      A + (size_t)(bm + w * 32 + (lane >> 2)) * K + kh * KH + (lane & 3) * 8;
  const unsigned short* Ap1 = Ap0 + (size_t)16 * K;
  const unsigned short* Bp0 =
      Bt + (size_t)(bn + w * 32 + (lane >> 2)) * K + kh * KH + (lane & 3) * 8;
  const unsigned short* Bp1 = Bp0 + (size_t)16 * K;
  unsigned short* AsD0 = &As[w * 1024];
  unsigned short* AsD1 = AsD0 + 512;
  unsigned short* BsD0 = &Bs[w * 1024];
  unsigned short* BsD1 = BsD0 + 512;

  const int fr = lane & 15;
  const int fk = (lane >> 4) * 8;

  for (int k0 = 0; k0 < KH; k0 += 32) {
    __syncthreads();
    glds16(Ap0 + k0, AsD0);
    glds16(Ap1 + k0, AsD1);
    glds16(Bp0 + k0, BsD0);
    glds16(Bp1 + k0, BsD1);
    __syncthreads();
    bf16x8 a[4], b[4];
#pragma unroll
    for (int im = 0; im < 4; ++im)
      a[im] = *(const bf16x8*)&As[(wm + im * 16 + fr) * 32 + fk];
#pragma unroll
    for (int in = 0; in < 4; ++in)
      b[in] = *(const bf16x8*)&Bs[(wn + in * 16 + fr) * 32 + fk];
#pragma unroll
    for (int im = 0; im < 4; ++im)
#pragma unroll
      for (int in = 0; in < 4; ++in)
        acc[im][in] = __builtin_amdgcn_mfma_f32_16x16x32_bf16(a[im], b[in], acc[im][in], 0, 0, 0);
  }

  unsigned short* P = Pp + (size_t)kh * (8u << 20);
#pragma unroll
  for (int im = 0; im < 4; ++im) {
    const int row0 = bm + wm + im * 16 + (lane >> 4) * 4;
#pragma unroll
    for (int in = 0; in < 4; ++in) {
      const int col = bn + wn + in * 16 + fr;
#pragma unroll
      for (int r = 0; r < 4; ++r)
        P[(size_t)(row0 + r) * N + col] = f2bf(acc[im][in][r]);
    }
  }
}

// ---------------- FF2 combine: out = x1 + b2 + P0 + P1 ----------------
__global__ __launch_bounds__(256) void ff2_reduce(const unsigned short* __restrict__ Pp,
                                                  const float* __restrict__ x1,
                                                  const float* __restrict__ b2,
                                                  float* __restrict__ out) {
  const int i = blockIdx.x * 256 + threadIdx.x;  // 2M float4 groups
  const size_t off = (size_t)i * 4;
  const ushort4 p0 = *(const ushort4*)(Pp + off);
  const ushort4 p1 = *(const ushort4*)(Pp + (8u << 20) + off);
  const float4 xv = *(const float4*)(x1 + off);
  const float4 bv = *(const float4*)(b2 + (off & 1023));
  float4 o;
  o.x = xv.x + bv.x + bf2f(p0.x) + bf2f(p1.x);
  o.y = xv.y + bv.y + bf2f(p0.y) + bf2f(p1.y);
  o.z = xv.z + bv.z + bf2f(p0.z) + bf2f(p1.z);
  o.w = xv.w + bv.w + bf2f(p0.w) + bf2f(p1.w);
  *(float4*)(out + off) = o;
}

// ---------------- bf16 MFMA GEMM 128x64 tile (O-proj: N=1024, K=1024) ----------
template <int OUT_BF16, int RELU, int RES>
__global__ __launch_bounds__(256) void gemm_n64(const unsigned short* __restrict__ A,
                                                const unsigned short* __restrict__ Bt,
                                                const float* __restrict__ bias,
                                                const float* __restrict__ res,
                                                void* __restrict__ C,
                                                int M, int N, int K) {
  __shared__ unsigned short As[128 * 32];
  __shared__ unsigned short Bs[64 * 32];
  const int tid = threadIdx.x;
  const int w = tid >> 6;
  const int lane = tid & 63;

  const int nbn = N >> 6;
  const int bm = (blockIdx.x / nbn) * 128;
  const int bn = (blockIdx.x % nbn) * 64;

  const int wm = (w & 1) * 64, wn = (w >> 1) * 32;

  f32x4 acc[4][2];
#pragma unroll
  for (int i = 0; i < 4; ++i)
#pragma unroll
    for (int j = 0; j < 2; ++j) acc[i][j] = (f32x4){0.f, 0.f, 0.f, 0.f};

  const unsigned short* Ap0 = A + (size_t)(bm + w * 32 + (lane >> 2)) * K + (lane & 3) * 8;
  const unsigned short* Ap1 = Ap0 + (size_t)16 * K;
  const unsigned short* Bp0 = Bt + (size_t)(bn + w * 16 + (lane >> 2)) * K + (lane & 3) * 8;
  unsigned short* AsD0 = &As[w * 1024];
  unsigned short* AsD1 = AsD0 + 512;
  unsigned short* BsD0 = &Bs[w * 512];

  const int fr = lane & 15;
  const int fk = (lane >> 4) * 8;

  for (int k0 = 0; k0 < K; k0 += 32) {
    __syncthreads();
    glds16(Ap0 + k0, AsD0);
    glds16(Ap1 + k0, AsD1);
    glds16(Bp0 + k0, BsD0);
    __syncthreads();
    bf16x8 a[4], b[2];
#pragma unroll
    for (int im = 0; im < 4; ++im)
      a[im] = *(const bf16x8*)&As[(wm + im * 16 + fr) * 32 + fk];
#pragma unroll
    for (int in = 0; in < 2; ++in)
      b[in] = *(const bf16x8*)&Bs[(wn + in * 16 + fr) * 32 + fk];
#pragma unroll
    for (int im = 0; im < 4; ++im)
#pragma unroll
      for (int in = 0; in < 2; ++in)
        acc[im][in] = __builtin_amdgcn_mfma_f32_16x16x32_bf16(a[im], b[in], acc[im][in], 0, 0, 0);
  }

#pragma unroll
  for (int im = 0; im < 4; ++im) {
    const int row0 = bm + wm + im * 16 + (lane >> 4) * 4;
#pragma unroll
    for (int in = 0; in < 2; ++in) {
      const int col = bn + wn + in * 16 + fr;
      const float bv = bias[col];
#pragma unroll
      for (int r = 0; r < 4; ++r) {
        float v = acc[im][in][r] + bv;
        if (RES) v += res[(size_t)(row0 + r) * N + col];
        if (RELU) v = fmaxf(v, 0.0f);
        if (OUT_BF16)
          ((unsigned short*)C)[(size_t)(row0 + r) * N + col] = f2bf(v);
        else
          ((float*)C)[(size_t)(row0 + r) * N + col] = v;
      }
    }
  }
}

// ---------------- QKV GEMM with fused RoPE (Q,K) + transposed V store ------------------
__global__ __launch_bounds__(256) void gemm_qkv(const unsigned short* __restrict__ A,
                                                const unsigned short* __restrict__ Bt,
                                                const float* __restrict__ bias,
                                                unsigned short* __restrict__ QKV,
                                                unsigned short* __restrict__ Vt,
                                                int M, int K) {
  const int N = 3072;
  __shared__ unsigned short As[128 * 32];
  __shared__ unsigned short Bs[128 * 32];
  const int tid = threadIdx.x;
  const int w = tid >> 6;
  const int lane = tid & 63;

  const int nb = gridDim.x;
  const int id = blockIdx.x;
  const int lid = (id & 7) * (nb >> 3) + (id >> 3);
  const int per = (M >> 7) * 8;
  const int grp = lid / per;
  const int rem = lid - grp * per;
  const int bn = (grp * 8 + (rem & 7)) * 128;
  const int bm = (rem >> 3) * 128;

  const int wm = (w & 1) * 64, wn = (w >> 1) * 64;

  f32x4 acc[4][4];
#pragma unroll
  for (int i = 0; i < 4; ++i)
#pragma unroll
    for (int j = 0; j < 4; ++j) acc[i][j] = (f32x4){0.f, 0.f, 0.f, 0.f};

  const unsigned short* Ap0 = A + (size_t)(bm + w * 32 + (lane >> 2)) * K + (lane & 3) * 8;
  const unsigned short* Ap1 = Ap0 + (size_t)16 * K;
  const unsigned short* Bp0 = Bt + (size_t)(bn + w * 32 + (lane >> 2)) * K + (lane & 3) * 8;
  const unsigned short* Bp1 = Bp0 + (size_t)16 * K;
  unsigned short* AsD0 = &As[w * 1024];
  unsigned short* AsD1 = AsD0 + 512;
  unsigned short* BsD0 = &Bs[w * 1024];
  unsigned short* BsD1 = BsD0 + 512;

  const int fr = lane & 15;
  const int fk = (lane >> 4) * 8;

  for (int k0 = 0; k0 < K; k0 += 32) {
    __syncthreads();
    glds16(Ap0 + k0, AsD0);
    glds16(Ap1 + k0, AsD1);
    glds16(Bp0 + k0, BsD0);
    glds16(Bp1 + k0, BsD1);
    __syncthreads();
    bf16x8 a[4], b[4];
#pragma unroll
    for (int im = 0; im < 4; ++im)
      a[im] = *(const bf16x8*)&As[(wm + im * 16 + fr) * 32 + fk];
#pragma unroll
    for (int in = 0; in < 4; ++in)
      b[in] = *(const bf16x8*)&Bs[(wn + in * 16 + fr) * 32 + fk];
#pragma unroll
    for (int im = 0; im < 4; ++im)
#pragma unroll
      for (int in = 0; in < 4; ++in)
        acc[im][in] = __builtin_amdgcn_mfma_f32_16x16x32_bf16(a[im], b[in], acc[im][in], 0, 0, 0);
  }

  const int cbase = bn + wn;
  const int seg = cbase >> 6;
  const int typ = seg >> 4;
  const int hh = seg & 15;
  const int bidx = bm >> 10;
  float bv[4];
#pragma unroll
  for (int in = 0; in < 4; ++in) bv[in] = bias[cbase + in * 16 + fr];

  if (typ == 2) {
#pragma unroll
    for (int im = 0; im < 4; ++im) {
      const int s0 = (bm & 1023) + wm + im * 16 + (lane >> 4) * 4;
#pragma unroll
      for (int in = 0; in < 4; ++in) {
        const int d = in * 16 + fr;
        ushort4 o4;
        o4.x = f2bf(acc[im][in][0] + bv[in]);
        o4.y = f2bf(acc[im][in][1] + bv[in]);
        o4.z = f2bf(acc[im][in][2] + bv[in]);
        o4.w = f2bf(acc[im][in][3] + bv[in]);
        *(ushort4*)&Vt[(size_t)((bidx * 16 + hh) * 64 + d) * S_ + s0] = o4;
      }
    }
  } else {
    const float qs = (typ == 0) ? QSCALE : 1.0f;
    const float i0 = exp2f(-LG2_10K * (float)fr);
    const float i1 = exp2f(-LG2_10K * (float)(fr + 16));
#pragma unroll
    for (int im = 0; im < 4; ++im) {
      const int row0 = bm + wm + im * 16 + (lane >> 4) * 4;
#pragma unroll
      for (int r = 0; r < 4; ++r) {
        const int row = row0 + r;
        const float s = (float)(row & 1023);
        float sn0, cs0, sn1, cs1;
        __sincosf(s * i0, &sn0, &cs0);
        __sincosf(s * i1, &sn1, &cs1);
        const float x0 = acc[im][0][r] + bv[0];
        const float x1 = acc[im][1][r] + bv[1];
        const float x2 = acc[im][2][r] + bv[2];
        const float x3 = acc[im][3][r] + bv[3];
        unsigned short* cp = QKV + (size_t)row * 3072 + cbase;
        cp[fr]      = f2bf((x0 * cs0 - x2 * sn0) * qs);
        cp[16 + fr] = f2bf((x1 * cs1 - x3 * sn1) * qs);
        cp[32 + fr] = f2bf((x2 * cs0 + x0 * sn0) * qs);
        cp[48 + fr] = f2bf((x3 * cs1 + x1 * sn1) * qs);
      }
    }
  }
}

// ---------------- MFMA flash attention v4: S^T form + double-buffered K/V staging -------
__global__ __launch_bounds__(256) void attn_v4(const unsigned short* __restrict__ QKV,
                                               const unsigned short* __restrict__ Vt,
                                               unsigned short* __restrict__ Og) {
  __shared__ unsigned short Kf[2][8 * 512];
  __shared__ unsigned short Vf[2][8 * 512];
  __shared__ unsigned short Ps[4][32 * 72];
  const int tid = threadIdx.x;
  const int w = tid >> 6, lane = tid & 63;
  const int qt = blockIdx.x, bh = blockIdx.y;
  const int b = bh >> 4, h = bh & 15;
  const int fr = lane & 15, g = lane >> 4, fk = g * 8;
  const int q0w = qt * 128 + w * 32;

  bf16x8 qB[2][2];
#pragma unroll
  for (int nt = 0; nt < 2; ++nt)
#pragma unroll
    for (int c = 0; c < 2; ++c)
      qB[nt][c] = *(const bf16x8*)&QKV[(size_t)(b * S_ + q0w + nt * 16 + fr) * 3072 +
                                       h * 64 + c * 32 + fk];

  f32x4 o[4][2];
#pragma unroll
  for (int mt = 0; mt < 4; ++mt)
#pragma unroll
    for (int nt = 0; nt < 2; ++nt) o[mt][nt] = (f32x4){0.f, 0.f, 0.f, 0.f};
  float l[2] = {0.0f, 0.0f};

#define STAGE(kt, bufi)                                                                   \
  {                                                                                       \
    _Pragma("unroll") for (int p = 0; p < 4; ++p) {                                       \
      const int u = w * 4 + p;                                                            \
      if (u < 8) {                                                                        \
        const int mt = u >> 1, c = u & 1;                                                 \
        glds16(QKV + (size_t)(b * S_ + (kt) * 64 + mt * 16 + fr) * 3072 + 1024 + h * 64 + \
                   c * 32 + fk,                                                           \
               &Kf[bufi][u * 512]);                                                       \
      } else {                                                                            \
        const int v2 = u - 8, mt = v2 >> 1, c = v2 & 1;                                   \
        glds16(Vt + (size_t)(bh * 64 + mt * 16 + fr) * S_ + (kt) * 64 + c * 32 + fk,      \
               &Vf[bufi][v2 * 512]);                                                      \
      }                                                                                   \
    }                                                                                     \
  }

  STAGE(0, 0);

  for (int kt = 0; kt < 16; ++kt) {
    __syncthreads();
    if (kt < 15) STAGE(kt + 1, (kt + 1) & 1);
    const unsigned short* Kc = Kf[kt & 1];
    const unsigned short* Vc = Vf[kt & 1];

    f32x4 s[4][2];
#pragma unroll
    for (int mt = 0; mt < 4; ++mt) {
      const bf16x8 k0 = *(const bf16x8*)&Kc[(mt * 2 + 0) * 512 + lane * 8];
      const bf16x8 k1 = *(const bf16x8*)&Kc[(mt * 2 + 1) * 512 + lane * 8];
#pragma unroll
      for (int nt = 0; nt < 2; ++nt) {
        f32x4 a = (f32x4){0.f, 0.f, 0.f, 0.f};
        a = __builtin_amdgcn_mfma_f32_16x16x32_bf16(k0, qB[nt][0], a, 0, 0, 0);
        a = __builtin_amdgcn_mfma_f32_16x16x32_bf16(k1, qB[nt][1], a, 0, 0, 0);
        s[mt][nt] = a;
      }
    }

#pragma unroll
    for (int nt = 0; nt < 2; ++nt) {
      float rs = 0.0f;
#pragma unroll
      for (int mt = 0; mt < 4; ++mt)
#pragma unroll
        for (int r = 0; r < 4; ++r) {
          const float p = exp2f(s[mt][nt][r]);
          s[mt][nt][r] = p;
          rs += p;
        }
      rs += __shfl_xor(rs, 16);
      rs += __shfl_xor(rs, 32);
      l[nt] += rs;
    }

#pragma unroll
    for (int nt = 0; nt < 2; ++nt)
#pragma unroll
      for (int mt = 0; mt < 4; ++mt) {
        uint2 pk;
        pk.x = __builtin_amdgcn_perm(fbits(s[mt][nt][1]), fbits(s[mt][nt][0]), 0x07060302u);
        pk.y = __builtin_amdgcn_perm(fbits(s[mt][nt][3]), fbits(s[mt][nt][2]), 0x07060302u);
        *(uint2*)&Ps[w][(nt * 16 + fr) * 72 + mt * 16 + g * 4] = pk;
      }

    bf16x8 pB[2][2];
#pragma unroll
    for (int nt = 0; nt < 2; ++nt)
#pragma unroll
      for (int c = 0; c < 2; ++c)
        pB[nt][c] = *(const bf16x8*)&Ps[w][(nt * 16 + fr) * 72 + c * 32 + fk];
#pragma unroll
    for (int mt = 0; mt < 4; ++mt) {
      const bf16x8 v0 = *(const bf16x8*)&Vc[(mt * 2 + 0) * 512 + lane * 8];
      const bf16x8 v1 = *(const bf16x8*)&Vc[(mt * 2 + 1) * 512 + lane * 8];
#pragma unroll
      for (int nt = 0; nt < 2; ++nt) {
        o[mt][nt] = __builtin_amdgcn_mfma_f32_16x16x32_bf16(v0, pB[nt][0], o[mt][nt], 0, 0, 0);
        o[mt][nt] = __builtin_amdgcn_mfma_f32_16x16x32_bf16(v1, pB[nt][1], o[mt][nt], 0, 0, 0);
      }
    }
  }

  const float linv0 = 1.0f / l[0], linv1 = 1.0f / l[1];
#pragma unroll
  for (int nt = 0; nt < 2; ++nt) {
    const float li = nt ? linv1 : linv0;
#pragma unroll
    for (int mt = 0; mt < 4; ++mt) {
      uint2 pk;
      pk.x = __builtin_amdgcn_perm(fbits(o[mt][nt][1] * li), fbits(o[mt][nt][0] * li), 0x07060302u);
      pk.y = __builtin_amdgcn_perm(fbits(o[mt][nt][3] * li), fbits(o[mt][nt][2] * li), 0x07060302u);
      *(uint2*)&Ps[w][(nt * 16 + fr) * 72 + mt * 16 + g * 4] = pk;
    }
  }
  const int qr = lane >> 1, hf = lane & 1;
#pragma unroll
  for (int c = 0; c < 2; ++c) {
    const bf16x8 vv = *(const bf16x8*)&Ps[w][qr * 72 + hf * 16 + c * 32];
    *(bf16x8*)&Og[(size_t)(b * S_ + q0w + qr) * E_ + h * 64 + hf * 16 + c * 32] = vv;
  }
}

extern "C" void kernel_launch(void* const* d_in, const int* in_sizes, int n_in,
                              void* d_out, int out_size, void* d_ws, size_t ws_size,
                              hipStream_t stream) {
  const float* x  = (const float*)d_in[0];
  const float* WQ = (const float*)d_in[1];
  const float* bQ = (const float*)d_in[2];
  const float* WK = (const float*)d_in[3];
  const float* bK = (const float*)d_in[4];
  const float* WV = (const float*)d_in[5];
  const float* bV = (const float*)d_in[6];
  const float* WO = (const float*)d_in[7];
  const float* bO = (const float*)d_in[8];
  const float* W1 = (const float*)d_in[9];
  const float* b1 = (const float*)d_in[10];
  const float* W2 = (const float*)d_in[11];
  const float* b2 = (const float*)d_in[12];
  const float* g1 = (const float*)d_in[13];
  const float* g2 = (const float*)d_in[14];
  float* out = (float*)d_out;

  char* ws = (char*)d_ws;
  const size_t MB = 1024 * 1024;
  unsigned short* h1   = (unsigned short*)(ws + 0 * MB);
  unsigned short* QKV  = (unsigned short*)(ws + 16 * MB);   // [8192,3072]
  unsigned short* Vt   = (unsigned short*)(ws + 64 * MB);   // [128*64,1024]
  unsigned short* Ob   = (unsigned short*)(ws + 80 * MB);
  float*          x1   = (float*)(ws + 96 * MB);
  unsigned short* h2   = (unsigned short*)(ws + 128 * MB);
  unsigned short* mid  = (unsigned short*)(ws + 16 * MB);   // reuses QKV+Vt region
  unsigned short* WQKVt= (unsigned short*)(ws + 144 * MB);
  unsigned short* WOt  = (unsigned short*)(ws + 150 * MB);
  unsigned short* W1t  = (unsigned short*)(ws + 152 * MB);
  unsigned short* W2t  = (unsigned short*)(ws + 160 * MB);
  float*          bqkv = (float*)(ws + 168 * MB);
  unsigned short* Pp   = (unsigned short*)(ws + 176 * MB);  // [2][8192,1024] bf16 partials

  const int M = B_ * S_;

  wconvT4<<<dim3(32, 32, 4), 256, 0, stream>>>(WQ, WK, WV, WO, WQKVt,
                                               WQKVt + 1024 * 1024,
                                               WQKVt + 2 * 1024 * 1024, WOt);
  wconvT<<<dim3(128, 32), 256, 0, stream>>>(W1, W1t, E_, FF_);
  wconvT<<<dim3(32, 128), 256, 0, stream>>>(W2, W2t, FF_, E_);
  bpack<<<12, 256, 0, stream>>>(bQ, bK, bV, bqkv);

  rmsnorm_kernel<<<M, 256, 0, stream>>>(x, g1, h1);

  gemm_qkv<<<24 * 64, 256, 0, stream>>>(h1, WQKVt, bqkv, QKV, Vt, M, E_);

  attn_v4<<<dim3(8, B_ * H_), 256, 0, stream>>>(QKV, Vt, Ob);

  gemm_n64<0, 0, 1><<<64 * 16, 256, 0, stream>>>(Ob, WOt, bO, x, x1, M, E_, E_);

  rmsnorm_kernel<<<M, 256, 0, stream>>>(x1, g2, h2);

  gemm_bf16<1, 1, 0><<<32 * 64, 256, 0, stream>>>(h2, W1t, b1, nullptr, mid, M, FF_, E_);

  gemm_sk2<<<1024, 256, 0, stream>>>(mid, W2t, Pp);

  ff2_reduce<<<8192, 256, 0, stream>>>(Pp, x1, b2, out);
}

// Round 7
// 495.152 us; speedup vs baseline: 8.7462x; 1.0859x over previous
//
#include <hip/hip_runtime.h>
#include <math.h>

#define B_ 8
#define S_ 1024
#define E_ 1024
#define H_ 16
#define FF_ 4096

typedef __attribute__((ext_vector_type(8))) short bf16x8;
typedef __attribute__((ext_vector_type(4))) float f32x4;

#define QSCALE 0.1803368801111f  // 0.125 * log2(e)
#define LG2_10K 0.4152410118f    // log2(10000)/32

__device__ __forceinline__ unsigned short f2bf(float f) {
  union { float f; unsigned u; } v;
  v.f = f;
  unsigned r = v.u + 0x7fffu + ((v.u >> 16) & 1u);
  return (unsigned short)(r >> 16);
}
__device__ __forceinline__ float bf2f(unsigned short u) {
  union { unsigned u; float f; } v;
  v.u = ((unsigned)u) << 16;
  return v.f;
}
__device__ __forceinline__ unsigned fbits(float f) {
  union { float f; unsigned u; } v;
  v.f = f;
  return v.u;
}

__device__ __forceinline__ void glds16(const void* g, void* l) {
  __builtin_amdgcn_global_load_lds(
      (const __attribute__((address_space(1))) unsigned int*)g,
      (__attribute__((address_space(3))) unsigned int*)l, 16, 0, 0);
}

// ---------------- prep: all weight converts (fp32 [K][N] -> bf16 [N][K]) + bias pack ----
// flat 32x32-tile job grid: [0,4096) four ExE mats; [4096,8192) W1; [8192,12288) W2;
// [12288,12300) bias pack.
__global__ __launch_bounds__(256) void prep(const float* __restrict__ WQ,
                                            const float* __restrict__ WK,
                                            const float* __restrict__ WV,
                                            const float* __restrict__ WO,
                                            const float* __restrict__ W1,
                                            const float* __restrict__ W2,
                                            const float* __restrict__ bQ,
                                            const float* __restrict__ bK,
                                            const float* __restrict__ bV,
                                            unsigned short* __restrict__ WQKVt,
                                            unsigned short* __restrict__ WOt,
                                            unsigned short* __restrict__ W1t,
                                            unsigned short* __restrict__ W2t,
                                            float* __restrict__ bqkv) {
  const int id = blockIdx.x;
  if (id >= 12288) {
    const int i = (id - 12288) * 256 + threadIdx.x;
    if (i < 3072)
      bqkv[i] = (i < 1024) ? bQ[i] : ((i < 2048) ? bK[i - 1024] : bV[i - 2048]);
    return;
  }
  const float* W;
  unsigned short* D;
  int K, N, x, y;
  if (id < 4096) {
    const int m = id >> 10;
    const float* ws4[4] = {WQ, WK, WV, WO};
    unsigned short* ds4[4] = {WQKVt, WQKVt + 1024 * 1024, WQKVt + 2 * 1024 * 1024, WOt};
    W = ws4[m]; D = ds4[m]; K = 1024; N = 1024;
    x = id & 31; y = (id >> 5) & 31;
  } else if (id < 8192) {
    const int j = id - 4096;
    W = W1; D = W1t; K = 1024; N = 4096;
    x = j & 127; y = j >> 7;
  } else {
    const int j = id - 8192;
    W = W2; D = W2t; K = 4096; N = 1024;
    x = j & 31; y = j >> 5;
  }
  __shared__ float t[32][33];
  const int tx = threadIdx.x & 31, ty = threadIdx.x >> 5;
  const int n0 = x * 32, k0 = y * 32;
#pragma unroll
  for (int p = 0; p < 4; ++p)
    t[ty + p * 8][tx] = W[(size_t)(k0 + ty + p * 8) * N + n0 + tx];
  __syncthreads();
#pragma unroll
  for (int p = 0; p < 4; ++p)
    D[(size_t)(n0 + ty + p * 8) * K + k0 + tx] = f2bf(t[tx][ty + p * 8]);
}

// ---------------- RMSNorm: fp32 in, bf16 out; one block per row ----------------
__global__ __launch_bounds__(256) void rmsnorm_kernel(const float* __restrict__ x,
                                                      const float* __restrict__ g,
                                                      unsigned short* __restrict__ out) {
  const int row = blockIdx.x;
  const int t = threadIdx.x;
  const float4 v = ((const float4*)(x + (size_t)row * E_))[t];
  float ss = v.x * v.x + v.y * v.y + v.z * v.z + v.w * v.w;
#pragma unroll
  for (int off = 32; off > 0; off >>= 1) ss += __shfl_down(ss, off);
  __shared__ float sred[4];
  if ((t & 63) == 0) sred[t >> 6] = ss;
  __syncthreads();
  const float tot = sred[0] + sred[1] + sred[2] + sred[3];
  const float rinv = rsqrtf(tot * (1.0f / E_) + 1.1920929e-07f);
  const float4 gv = ((const float4*)g)[t];
  ushort4 o;
  o.x = f2bf(v.x * rinv * gv.x);
  o.y = f2bf(v.y * rinv * gv.y);
  o.z = f2bf(v.z * rinv * gv.z);
  o.w = f2bf(v.w * rinv * gv.w);
  ((ushort4*)(out + (size_t)row * E_))[t] = o;
}

// ======== BK=64 XOR-swizzled staging helpers ========
// LDS unit = 1024 B = 8 rows x 128 B. Lane l of a unit: row = l>>3, 16B slot = l&7.
// Content placed at slot s of row r is logical k-slot (s ^ (r&7)); reader computes
// phys = logical ^ (r&7). glds LDS dest stays linear (base + lane*16).

// ---------------- bf16 MFMA GEMM 128x128, BK=64, XCD-swizzled 1D grid ------------
template <int OUT_BF16, int RELU, int RES>
__global__ __launch_bounds__(256) void gemm_bf16(const unsigned short* __restrict__ A,
                                                 const unsigned short* __restrict__ Bt,
                                                 const float* __restrict__ bias,
                                                 const float* __restrict__ res,
                                                 void* __restrict__ C,
                                                 int M, int N, int K) {
  __shared__ unsigned short As[128 * 64];
  __shared__ unsigned short Bs[128 * 64];
  const int tid = threadIdx.x;
  const int w = tid >> 6;
  const int lane = tid & 63;

  const int nb = gridDim.x;
  const int id = blockIdx.x;
  const int lid = (id & 7) * (nb >> 3) + (id >> 3);
  const int per = (M >> 7) * 8;
  const int grp = lid / per;
  const int rem = lid - grp * per;
  const int bn = (grp * 8 + (rem & 7)) * 128;
  const int bm = (rem >> 3) * 128;

  const int wm = (w & 1) * 64, wn = (w >> 1) * 64;

  f32x4 acc[4][4];
#pragma unroll
  for (int i = 0; i < 4; ++i)
#pragma unroll
    for (int j = 0; j < 4; ++j) acc[i][j] = (f32x4){0.f, 0.f, 0.f, 0.f};

  const int srow = lane >> 3;
  const int skb = (lane & 7) ^ srow;  // swizzled source 16B-slot
  const unsigned short* Ap[4];
  const unsigned short* Bp[4];
  unsigned short* AsD[4];
  unsigned short* BsD[4];
#pragma unroll
  for (int p = 0; p < 4; ++p) {
    const int u = w * 4 + p;
    Ap[p] = A + (size_t)(bm + u * 8 + srow) * K + skb * 8;
    Bp[p] = Bt + (size_t)(bn + u * 8 + srow) * K + skb * 8;
    AsD[p] = &As[u * 512 + lane * 8];
    BsD[p] = &Bs[u * 512 + lane * 8];
  }

  const int fr = lane & 15;
  const int g = lane >> 4;
  const int sw = fr & 7;

  for (int k0 = 0; k0 < K; k0 += 64) {
    __syncthreads();
#pragma unroll
    for (int p = 0; p < 4; ++p) glds16(Ap[p] + k0, AsD[p]);
#pragma unroll
    for (int p = 0; p < 4; ++p) glds16(Bp[p] + k0, BsD[p]);
    __syncthreads();
    bf16x8 a[4][2], b[4][2];
#pragma unroll
    for (int im = 0; im < 4; ++im)
#pragma unroll
      for (int kc = 0; kc < 2; ++kc)
        a[im][kc] = *(const bf16x8*)&As[(wm + im * 16 + fr) * 64 + ((kc * 4 + g) ^ sw) * 8];
#pragma unroll
    for (int in = 0; in < 4; ++in)
#pragma unroll
      for (int kc = 0; kc < 2; ++kc)
        b[in][kc] = *(const bf16x8*)&Bs[(wn + in * 16 + fr) * 64 + ((kc * 4 + g) ^ sw) * 8];
#pragma unroll
    for (int im = 0; im < 4; ++im)
#pragma unroll
      for (int in = 0; in < 4; ++in) {
        acc[im][in] = __builtin_amdgcn_mfma_f32_16x16x32_bf16(a[im][0], b[in][0], acc[im][in], 0, 0, 0);
        acc[im][in] = __builtin_amdgcn_mfma_f32_16x16x32_bf16(a[im][1], b[in][1], acc[im][in], 0, 0, 0);
      }
  }

#pragma unroll
  for (int im = 0; im < 4; ++im) {
    const int row0 = bm + wm + im * 16 + (lane >> 4) * 4;
#pragma unroll
    for (int in = 0; in < 4; ++in) {
      const int col = bn + wn + in * 16 + fr;
      const float bv = bias[col];
#pragma unroll
      for (int r = 0; r < 4; ++r) {
        float v = acc[im][in][r] + bv;
        if (RES) v += res[(size_t)(row0 + r) * N + col];
        if (RELU) v = fmaxf(v, 0.0f);
        if (OUT_BF16)
          ((unsigned short*)C)[(size_t)(row0 + r) * N + col] = f2bf(v);
        else
          ((float*)C)[(size_t)(row0 + r) * N + col] = v;
      }
    }
  }
}

// ---------------- split-K=2 GEMM for FF2 (M=8192,N=1024,K=4096), BK=64 ----------
__global__ __launch_bounds__(256) void gemm_sk2(const unsigned short* __restrict__ A,
                                                const unsigned short* __restrict__ Bt,
                                                unsigned short* __restrict__ Pp) {
  const int N = 1024, K = 4096, KH = 2048;
  __shared__ unsigned short As[128 * 64];
  __shared__ unsigned short Bs[128 * 64];
  const int tid = threadIdx.x;
  const int w = tid >> 6;
  const int lane = tid & 63;

  const int id = blockIdx.x;
  const int kh = id >> 9;
  const int hid = id & 511;
  const int lid = (hid & 7) * 64 + (hid >> 3);
  const int bn = (lid & 7) * 128;
  const int bm = (lid >> 3) * 128;

  const int wm = (w & 1) * 64, wn = (w >> 1) * 64;

  f32x4 acc[4][4];
#pragma unroll
  for (int i = 0; i < 4; ++i)
#pragma unroll
    for (int j = 0; j < 4; ++j) acc[i][j] = (f32x4){0.f, 0.f, 0.f, 0.f};

  const int srow = lane >> 3;
  const int skb = (lane & 7) ^ srow;
  const unsigned short* Ap[4];
  const unsigned short* Bp[4];
  unsigned short* AsD[4];
  unsigned short* BsD[4];
#pragma unroll
  for (int p = 0; p < 4; ++p) {
    const int u = w * 4 + p;
    Ap[p] = A + (size_t)(bm + u * 8 + srow) * K + kh * KH + skb * 8;
    Bp[p] = Bt + (size_t)(bn + u * 8 + srow) * K + kh * KH + skb * 8;
    AsD[p] = &As[u * 512 + lane * 8];
    BsD[p] = &Bs[u * 512 + lane * 8];
  }

  const int fr = lane & 15;
  const int g = lane >> 4;
  const int sw = fr & 7;

  for (int k0 = 0; k0 < KH; k0 += 64) {
    __syncthreads();
#pragma unroll
    for (int p = 0; p < 4; ++p) glds16(Ap[p] + k0, AsD[p]);
#pragma unroll
    for (int p = 0; p < 4; ++p) glds16(Bp[p] + k0, BsD[p]);
    __syncthreads();
    bf16x8 a[4][2], b[4][2];
#pragma unroll
    for (int im = 0; im < 4; ++im)
#pragma unroll
      for (int kc = 0; kc < 2; ++kc)
        a[im][kc] = *(const bf16x8*)&As[(wm + im * 16 + fr) * 64 + ((kc * 4 + g) ^ sw) * 8];
#pragma unroll
    for (int in = 0; in < 4; ++in)
#pragma unroll
      for (int kc = 0; kc < 2; ++kc)
        b[in][kc] = *(const bf16x8*)&Bs[(wn + in * 16 + fr) * 64 + ((kc * 4 + g) ^ sw) * 8];
#pragma unroll
    for (int im = 0; im < 4; ++im)
#pragma unroll
      for (int in = 0; in < 4; ++in) {
        acc[im][in] = __builtin_amdgcn_mfma_f32_16x16x32_bf16(a[im][0], b[in][0], acc[im][in], 0, 0, 0);
        acc[im][in] = __builtin_amdgcn_mfma_f32_16x16x32_bf16(a[im][1], b[in][1], acc[im][in], 0, 0, 0);
      }
  }

  unsigned short* P = Pp + (size_t)kh * (8u << 20);
#pragma unroll
  for (int im = 0; im < 4; ++im) {
    const int row0 = bm + wm + im * 16 + (lane >> 4) * 4;
#pragma unroll
    for (int in = 0; in < 4; ++in) {
      const int col = bn + wn + in * 16 + fr;
#pragma unroll
      for (int r = 0; r < 4; ++r)
        P[(size_t)(row0 + r) * N + col] = f2bf(acc[im][in][r]);
    }
  }
}

// ---------------- FF2 combine: out = x1 + b2 + P0 + P1 ----------------
__global__ __launch_bounds__(256) void ff2_reduce(const unsigned short* __restrict__ Pp,
                                                  const float* __restrict__ x1,
                                                  const float* __restrict__ b2,
                                                  float* __restrict__ out) {
  const int i = blockIdx.x * 256 + threadIdx.x;
  const size_t off = (size_t)i * 4;
  const ushort4 p0 = *(const ushort4*)(Pp + off);
  const ushort4 p1 = *(const ushort4*)(Pp + (8u << 20) + off);
  const float4 xv = *(const float4*)(x1 + off);
  const float4 bv = *(const float4*)(b2 + (off & 1023));
  float4 o;
  o.x = xv.x + bv.x + bf2f(p0.x) + bf2f(p1.x);
  o.y = xv.y + bv.y + bf2f(p0.y) + bf2f(p1.y);
  o.z = xv.z + bv.z + bf2f(p0.z) + bf2f(p1.z);
  o.w = xv.w + bv.w + bf2f(p0.w) + bf2f(p1.w);
  *(float4*)(out + off) = o;
}

// ---------------- bf16 MFMA GEMM 128x64 tile, BK=64 (O-proj) ----------
template <int OUT_BF16, int RELU, int RES>
__global__ __launch_bounds__(256) void gemm_n64(const unsigned short* __restrict__ A,
                                                const unsigned short* __restrict__ Bt,
                                                const float* __restrict__ bias,
                                                const float* __restrict__ res,
                                                void* __restrict__ C,
                                                int M, int N, int K) {
  __shared__ unsigned short As[128 * 64];
  __shared__ unsigned short Bs[64 * 64];
  const int tid = threadIdx.x;
  const int w = tid >> 6;
  const int lane = tid & 63;

  const int nbn = N >> 6;
  const int bm = (blockIdx.x / nbn) * 128;
  const int bn = (blockIdx.x % nbn) * 64;

  const int wm = (w & 1) * 64, wn = (w >> 1) * 32;

  f32x4 acc[4][2];
#pragma unroll
  for (int i = 0; i < 4; ++i)
#pragma unroll
    for (int j = 0; j < 2; ++j) acc[i][j] = (f32x4){0.f, 0.f, 0.f, 0.f};

  const int srow = lane >> 3;
  const int skb = (lane & 7) ^ srow;
  const unsigned short* Ap[4];
  const unsigned short* Bp[2];
  unsigned short* AsD[4];
  unsigned short* BsD[2];
#pragma unroll
  for (int p = 0; p < 4; ++p) {
    const int u = w * 4 + p;
    Ap[p] = A + (size_t)(bm + u * 8 + srow) * K + skb * 8;
    AsD[p] = &As[u * 512 + lane * 8];
  }
#pragma unroll
  for (int p = 0; p < 2; ++p) {
    const int u = w * 2 + p;
    Bp[p] = Bt + (size_t)(bn + u * 8 + srow) * K + skb * 8;
    BsD[p] = &Bs[u * 512 + lane * 8];
  }

  const int fr = lane & 15;
  const int g = lane >> 4;
  const int sw = fr & 7;

  for (int k0 = 0; k0 < K; k0 += 64) {
    __syncthreads();
#pragma unroll
    for (int p = 0; p < 4; ++p) glds16(Ap[p] + k0, AsD[p]);
#pragma unroll
    for (int p = 0; p < 2; ++p) glds16(Bp[p] + k0, BsD[p]);
    __syncthreads();
    bf16x8 a[4][2], b[2][2];
#pragma unroll
    for (int im = 0; im < 4; ++im)
#pragma unroll
      for (int kc = 0; kc < 2; ++kc)
        a[im][kc] = *(const bf16x8*)&As[(wm + im * 16 + fr) * 64 + ((kc * 4 + g) ^ sw) * 8];
#pragma unroll
    for (int in = 0; in < 2; ++in)
#pragma unroll
      for (int kc = 0; kc < 2; ++kc)
        b[in][kc] = *(const bf16x8*)&Bs[(wn + in * 16 + fr) * 64 + ((kc * 4 + g) ^ sw) * 8];
#pragma unroll
    for (int im = 0; im < 4; ++im)
#pragma unroll
      for (int in = 0; in < 2; ++in) {
        acc[im][in] = __builtin_amdgcn_mfma_f32_16x16x32_bf16(a[im][0], b[in][0], acc[im][in], 0, 0, 0);
        acc[im][in] = __builtin_amdgcn_mfma_f32_16x16x32_bf16(a[im][1], b[in][1], acc[im][in], 0, 0, 0);
      }
  }

#pragma unroll
  for (int im = 0; im < 4; ++im) {
    const int row0 = bm + wm + im * 16 + (lane >> 4) * 4;
#pragma unroll
    for (int in = 0; in < 2; ++in) {
      const int col = bn + wn + in * 16 + fr;
      const float bv = bias[col];
#pragma unroll
      for (int r = 0; r < 4; ++r) {
        float v = acc[im][in][r] + bv;
        if (RES) v += res[(size_t)(row0 + r) * N + col];
        if (RELU) v = fmaxf(v, 0.0f);
        if (OUT_BF16)
          ((unsigned short*)C)[(size_t)(row0 + r) * N + col] = f2bf(v);
        else
          ((float*)C)[(size_t)(row0 + r) * N + col] = v;
      }
    }
  }
}

// ---------------- QKV GEMM (BK=64) with fused RoPE (Q,K) + transposed V store ----------
__global__ __launch_bounds__(256) void gemm_qkv(const unsigned short* __restrict__ A,
                                                const unsigned short* __restrict__ Bt,
                                                const float* __restrict__ bias,
                                                unsigned short* __restrict__ QKV,
                                                unsigned short* __restrict__ Vt,
                                                int M, int K) {
  __shared__ unsigned short As[128 * 64];
  __shared__ unsigned short Bs[128 * 64];
  const int tid = threadIdx.x;
  const int w = tid >> 6;
  const int lane = tid & 63;

  const int nb = gridDim.x;
  const int id = blockIdx.x;
  const int lid = (id & 7) * (nb >> 3) + (id >> 3);
  const int per = (M >> 7) * 8;
  const int grp = lid / per;
  const int rem = lid - grp * per;
  const int bn = (grp * 8 + (rem & 7)) * 128;
  const int bm = (rem >> 3) * 128;

  const int wm = (w & 1) * 64, wn = (w >> 1) * 64;

  f32x4 acc[4][4];
#pragma unroll
  for (int i = 0; i < 4; ++i)
#pragma unroll
    for (int j = 0; j < 4; ++j) acc[i][j] = (f32x4){0.f, 0.f, 0.f, 0.f};

  const int srow = lane >> 3;
  const int skb = (lane & 7) ^ srow;
  const unsigned short* Ap[4];
  const unsigned short* Bp[4];
  unsigned short* AsD[4];
  unsigned short* BsD[4];
#pragma unroll
  for (int p = 0; p < 4; ++p) {
    const int u = w * 4 + p;
    Ap[p] = A + (size_t)(bm + u * 8 + srow) * K + skb * 8;
    Bp[p] = Bt + (size_t)(bn + u * 8 + srow) * K + skb * 8;
    AsD[p] = &As[u * 512 + lane * 8];
    BsD[p] = &Bs[u * 512 + lane * 8];
  }

  const int fr = lane & 15;
  const int g = lane >> 4;
  const int sw = fr & 7;

  for (int k0 = 0; k0 < K; k0 += 64) {
    __syncthreads();
#pragma unroll
    for (int p = 0; p < 4; ++p) glds16(Ap[p] + k0, AsD[p]);
#pragma unroll
    for (int p = 0; p < 4; ++p) glds16(Bp[p] + k0, BsD[p]);
    __syncthreads();
    bf16x8 a[4][2], b[4][2];
#pragma unroll
    for (int im = 0; im < 4; ++im)
#pragma unroll
      for (int kc = 0; kc < 2; ++kc)
        a[im][kc] = *(const bf16x8*)&As[(wm + im * 16 + fr) * 64 + ((kc * 4 + g) ^ sw) * 8];
#pragma unroll
    for (int in = 0; in < 4; ++in)
#pragma unroll
      for (int kc = 0; kc < 2; ++kc)
        b[in][kc] = *(const bf16x8*)&Bs[(wn + in * 16 + fr) * 64 + ((kc * 4 + g) ^ sw) * 8];
#pragma unroll
    for (int im = 0; im < 4; ++im)
#pragma unroll
      for (int in = 0; in < 4; ++in) {
        acc[im][in] = __builtin_amdgcn_mfma_f32_16x16x32_bf16(a[im][0], b[in][0], acc[im][in], 0, 0, 0);
        acc[im][in] = __builtin_amdgcn_mfma_f32_16x16x32_bf16(a[im][1], b[in][1], acc[im][in], 0, 0, 0);
      }
  }

  const int cbase = bn + wn;
  const int seg = cbase >> 6;
  const int typ = seg >> 4;
  const int hh = seg & 15;
  const int bidx = bm >> 10;
  float bv[4];
#pragma unroll
  for (int in = 0; in < 4; ++in) bv[in] = bias[cbase + in * 16 + fr];

  if (typ == 2) {
#pragma unroll
    for (int im = 0; im < 4; ++im) {
      const int s0 = (bm & 1023) + wm + im * 16 + (lane >> 4) * 4;
#pragma unroll
      for (int in = 0; in < 4; ++in) {
        const int d = in * 16 + fr;
        ushort4 o4;
        o4.x = f2bf(acc[im][in][0] + bv[in]);
        o4.y = f2bf(acc[im][in][1] + bv[in]);
        o4.z = f2bf(acc[im][in][2] + bv[in]);
        o4.w = f2bf(acc[im][in][3] + bv[in]);
        *(ushort4*)&Vt[(size_t)((bidx * 16 + hh) * 64 + d) * S_ + s0] = o4;
      }
    }
  } else {
    const float qs = (typ == 0) ? QSCALE : 1.0f;
    const float i0 = exp2f(-LG2_10K * (float)fr);
    const float i1 = exp2f(-LG2_10K * (float)(fr + 16));
#pragma unroll
    for (int im = 0; im < 4; ++im) {
      const int row0 = bm + wm + im * 16 + (lane >> 4) * 4;
#pragma unroll
      for (int r = 0; r < 4; ++r) {
        const int row = row0 + r;
        const float s = (float)(row & 1023);
        float sn0, cs0, sn1, cs1;
        __sincosf(s * i0, &sn0, &cs0);
        __sincosf(s * i1, &sn1, &cs1);
        const float x0 = acc[im][0][r] + bv[0];
        const float x1 = acc[im][1][r] + bv[1];
        const float x2 = acc[im][2][r] + bv[2];
        const float x3 = acc[im][3][r] + bv[3];
        unsigned short* cp = QKV + (size_t)row * 3072 + cbase;
        cp[fr]      = f2bf((x0 * cs0 - x2 * sn0) * qs);
        cp[16 + fr] = f2bf((x1 * cs1 - x3 * sn1) * qs);
        cp[32 + fr] = f2bf((x2 * cs0 + x0 * sn0) * qs);
        cp[48 + fr] = f2bf((x3 * cs1 + x1 * sn1) * qs);
      }
    }
  }
}

// ---------------- MFMA flash attention v4: S^T form + double-buffered K/V staging -------
__global__ __launch_bounds__(256) void attn_v4(const unsigned short* __restrict__ QKV,
                                               const unsigned short* __restrict__ Vt,
                                               unsigned short* __restrict__ Og) {
  __shared__ unsigned short Kf[2][8 * 512];
  __shared__ unsigned short Vf[2][8 * 512];
  __shared__ unsigned short Ps[4][32 * 72];
  const int tid = threadIdx.x;
  const int w = tid >> 6, lane = tid & 63;
  const int qt = blockIdx.x, bh = blockIdx.y;
  const int b = bh >> 4, h = bh & 15;
  const int fr = lane & 15, g = lane >> 4, fk = g * 8;
  const int q0w = qt * 128 + w * 32;

  bf16x8 qB[2][2];
#pragma unroll
  for (int nt = 0; nt < 2; ++nt)
#pragma unroll
    for (int c = 0; c < 2; ++c)
      qB[nt][c] = *(const bf16x8*)&QKV[(size_t)(b * S_ + q0w + nt * 16 + fr) * 3072 +
                                       h * 64 + c * 32 + fk];

  f32x4 o[4][2];
#pragma unroll
  for (int mt = 0; mt < 4; ++mt)
#pragma unroll
    for (int nt = 0; nt < 2; ++nt) o[mt][nt] = (f32x4){0.f, 0.f, 0.f, 0.f};
  float l[2] = {0.0f, 0.0f};

#define STAGE(kt, bufi)                                                                   \
  {                                                                                       \
    _Pragma("unroll") for (int p = 0; p < 4; ++p) {                                       \
      const int u = w * 4 + p;                                                            \
      if (u < 8) {                                                                        \
        const int mt = u >> 1, c = u & 1;                                                 \
        glds16(QKV + (size_t)(b * S_ + (kt) * 64 + mt * 16 + fr) * 3072 + 1024 + h * 64 + \
                   c * 32 + fk,                                                           \
               &Kf[bufi][u * 512]);                                                       \
      } else {                                                                            \
        const int v2 = u - 8, mt = v2 >> 1, c = v2 & 1;                                   \
        glds16(Vt + (size_t)(bh * 64 + mt * 16 + fr) * S_ + (kt) * 64 + c * 32 + fk,      \
               &Vf[bufi][v2 * 512]);                                                      \
      }                                                                                   \
    }                                                                                     \
  }

  STAGE(0, 0);

  for (int kt = 0; kt < 16; ++kt) {
    __syncthreads();
    if (kt < 15) STAGE(kt + 1, (kt + 1) & 1);
    const unsigned short* Kc = Kf[kt & 1];
    const unsigned short* Vc = Vf[kt & 1];

    f32x4 s[4][2];
#pragma unroll
    for (int mt = 0; mt < 4; ++mt) {
      const bf16x8 k0 = *(const bf16x8*)&Kc[(mt * 2 + 0) * 512 + lane * 8];
      const bf16x8 k1 = *(const bf16x8*)&Kc[(mt * 2 + 1) * 512 + lane * 8];
#pragma unroll
      for (int nt = 0; nt < 2; ++nt) {
        f32x4 a = (f32x4){0.f, 0.f, 0.f, 0.f};
        a = __builtin_amdgcn_mfma_f32_16x16x32_bf16(k0, qB[nt][0], a, 0, 0, 0);
        a = __builtin_amdgcn_mfma_f32_16x16x32_bf16(k1, qB[nt][1], a, 0, 0, 0);
        s[mt][nt] = a;
      }
    }

#pragma unroll
    for (int nt = 0; nt < 2; ++nt) {
      float rs = 0.0f;
#pragma unroll
      for (int mt = 0; mt < 4; ++mt)
#pragma unroll
        for (int r = 0; r < 4; ++r) {
          const float p = exp2f(s[mt][nt][r]);
          s[mt][nt][r] = p;
          rs += p;
        }
      rs += __shfl_xor(rs, 16);
      rs += __shfl_xor(rs, 32);
      l[nt] += rs;
    }

#pragma unroll
    for (int nt = 0; nt < 2; ++nt)
#pragma unroll
      for (int mt = 0; mt < 4; ++mt) {
        uint2 pk;
        pk.x = __builtin_amdgcn_perm(fbits(s[mt][nt][1]), fbits(s[mt][nt][0]), 0x07060302u);
        pk.y = __builtin_amdgcn_perm(fbits(s[mt][nt][3]), fbits(s[mt][nt][2]), 0x07060302u);
        *(uint2*)&Ps[w][(nt * 16 + fr) * 72 + mt * 16 + g * 4] = pk;
      }

    bf16x8 pB[2][2];
#pragma unroll
    for (int nt = 0; nt < 2; ++nt)
#pragma unroll
      for (int c = 0; c < 2; ++c)
        pB[nt][c] = *(const bf16x8*)&Ps[w][(nt * 16 + fr) * 72 + c * 32 + fk];
#pragma unroll
    for (int mt = 0; mt < 4; ++mt) {
      const bf16x8 v0 = *(const bf16x8*)&Vc[(mt * 2 + 0) * 512 + lane * 8];
      const bf16x8 v1 = *(const bf16x8*)&Vc[(mt * 2 + 1) * 512 + lane * 8];
#pragma unroll
      for (int nt = 0; nt < 2; ++nt) {
        o[mt][nt] = __builtin_amdgcn_mfma_f32_16x16x32_bf16(v0, pB[nt][0], o[mt][nt], 0, 0, 0);
        o[mt][nt] = __builtin_amdgcn_mfma_f32_16x16x32_bf16(v1, pB[nt][1], o[mt][nt], 0, 0, 0);
      }
    }
  }

  const float linv0 = 1.0f / l[0], linv1 = 1.0f / l[1];
#pragma unroll
  for (int nt = 0; nt < 2; ++nt) {
    const float li = nt ? linv1 : linv0;
#pragma unroll
    for (int mt = 0; mt < 4; ++mt) {
      uint2 pk;
      pk.x = __builtin_amdgcn_perm(fbits(o[mt][nt][1] * li), fbits(o[mt][nt][0] * li), 0x07060302u);
      pk.y = __builtin_amdgcn_perm(fbits(o[mt][nt][3] * li), fbits(o[mt][nt][2] * li), 0x07060302u);
      *(uint2*)&Ps[w][(nt * 16 + fr) * 72 + mt * 16 + g * 4] = pk;
    }
  }
  const int qr = lane >> 1, hf = lane & 1;
#pragma unroll
  for (int c = 0; c < 2; ++c) {
    const bf16x8 vv = *(const bf16x8*)&Ps[w][qr * 72 + hf * 16 + c * 32];
    *(bf16x8*)&Og[(size_t)(b * S_ + q0w + qr) * E_ + h * 64 + hf * 16 + c * 32] = vv;
  }
}

extern "C" void kernel_launch(void* const* d_in, const int* in_sizes, int n_in,
                              void* d_out, int out_size, void* d_ws, size_t ws_size,
                              hipStream_t stream) {
  const float* x  = (const float*)d_in[0];
  const float* WQ = (const float*)d_in[1];
  const float* bQ = (const float*)d_in[2];
  const float* WK = (const float*)d_in[3];
  const float* bK = (const float*)d_in[4];
  const float* WV = (const float*)d_in[5];
  const float* bV = (const float*)d_in[6];
  const float* WO = (const float*)d_in[7];
  const float* bO = (const float*)d_in[8];
  const float* W1 = (const float*)d_in[9];
  const float* b1 = (const float*)d_in[10];
  const float* W2 = (const float*)d_in[11];
  const float* b2 = (const float*)d_in[12];
  const float* g1 = (const float*)d_in[13];
  const float* g2 = (const float*)d_in[14];
  float* out = (float*)d_out;

  char* ws = (char*)d_ws;
  const size_t MB = 1024 * 1024;
  unsigned short* h1   = (unsigned short*)(ws + 0 * MB);
  unsigned short* QKV  = (unsigned short*)(ws + 16 * MB);   // [8192,3072]
  unsigned short* Vt   = (unsigned short*)(ws + 64 * MB);   // [128*64,1024]
  unsigned short* Ob   = (unsigned short*)(ws + 80 * MB);
  float*          x1   = (float*)(ws + 96 * MB);
  unsigned short* h2   = (unsigned short*)(ws + 128 * MB);
  unsigned short* mid  = (unsigned short*)(ws + 16 * MB);   // reuses QKV+Vt region
  unsigned short* WQKVt= (unsigned short*)(ws + 144 * MB);
  unsigned short* WOt  = (unsigned short*)(ws + 150 * MB);
  unsigned short* W1t  = (unsigned short*)(ws + 152 * MB);
  unsigned short* W2t  = (unsigned short*)(ws + 160 * MB);
  float*          bqkv = (float*)(ws + 168 * MB);
  unsigned short* Pp   = (unsigned short*)(ws + 176 * MB);  // [2][8192,1024] bf16 partials

  const int M = B_ * S_;

  prep<<<12300, 256, 0, stream>>>(WQ, WK, WV, WO, W1, W2, bQ, bK, bV,
                                  WQKVt, WOt, W1t, W2t, bqkv);

  rmsnorm_kernel<<<M, 256, 0, stream>>>(x, g1, h1);

  gemm_qkv<<<24 * 64, 256, 0, stream>>>(h1, WQKVt, bqkv, QKV, Vt, M, E_);

  attn_v4<<<dim3(8, B_ * H_), 256, 0, stream>>>(QKV, Vt, Ob);

  gemm_n64<0, 0, 1><<<64 * 16, 256, 0, stream>>>(Ob, WOt, bO, x, x1, M, E_, E_);

  rmsnorm_kernel<<<M, 256, 0, stream>>>(x1, g2, h2);

  gemm_bf16<1, 1, 0><<<32 * 64, 256, 0, stream>>>(h2, W1t, b1, nullptr, mid, M, FF_, E_);

  gemm_sk2<<<1024, 256, 0, stream>>>(mid, W2t, Pp);

  ff2_reduce<<<8192, 256, 0, stream>>>(Pp, x1, b2, out);
}